// Round 6
// baseline (3272.453 us; speedup 1.0000x reference)
//
#include <hip/hip_runtime.h>

#define DD 1024
#define HH 2048
#define TT 4096
#define CC 512
#define PPc 16
#define SB 1040   // per-batch aug rows
#define KA 1088   // padded attention K (multiple of 64)
#define FFd 4096
#define NCH 8

typedef _Float16 f16x8 __attribute__((ext_vector_type(8)));
typedef float f32x4 __attribute__((ext_vector_type(4)));

typedef const __attribute__((address_space(1))) _Float16* gas_t;
typedef __attribute__((address_space(3))) _Float16* las_t;

__device__ __forceinline__ void async_cp16(const _Float16* g, _Float16* l) {
    __builtin_amdgcn_global_load_lds((gas_t)g, (las_t)l, 16, 0, 0);
}

template<int N> __device__ __forceinline__ void waitvm() {
    static_assert(N == 0 || N == 2 || N == 3 || N == 4 || N == 6 || N == 8, "unsupported vmcnt");
    if constexpr (N == 0)      asm volatile("s_waitcnt vmcnt(0)" ::: "memory");
    else if constexpr (N == 2) asm volatile("s_waitcnt vmcnt(2)" ::: "memory");
    else if constexpr (N == 3) asm volatile("s_waitcnt vmcnt(3)" ::: "memory");
    else if constexpr (N == 4) asm volatile("s_waitcnt vmcnt(4)" ::: "memory");
    else if constexpr (N == 6) asm volatile("s_waitcnt vmcnt(6)" ::: "memory");
    else                       asm volatile("s_waitcnt vmcnt(8)" ::: "memory");
}
#define BARRIER() asm volatile("s_barrier" ::: "memory")

struct GP {
    const _Float16* A; long bsA;
    const _Float16* Bt; long bsB;
    const float* bias;
    const float* resid; long ldr, bsR;
    const float* aux;   long ldx, bsX;
    float* Cf; long ldc, bsC;
    _Float16* Ch; long ldh, bsH;
    _Float16* Ct; long ldt, bsT;
    float* Mom;
    float* Cf2;
    float s1, s2;
    int M, N, K, act;
};

// acts: 0 plain, 1 silu (Cf<-raw, Ch/Ct<-silu*s1+resid), 2 mul-by-dsilu(aux),
//       4 routing (n<1024 -> Ch(+Ct), <2048 -> Cf, else Cf2; all ld 1024)
// K % 64 == 0, K >= 192 (3 prologue panels). Ct GEMMs require M % 8 == 0.
// Pipeline: 4 LDS buffers of 64-k panels, prefetch distance 3, counted vmcnt,
// raw s_barrier. LDS slots XOR-swizzled (T2): global source pre-swizzled so
// global_load_lds stays linear; ds_read applies the same involution.
template<int BM, int BN>
__global__ __launch_bounds__(256) void gemm16(GP g)
{
    constexpr int WM = BM / 2, WN = BN / 2;
    constexpr int FA = WM / 16, FB = WN / 16;
    constexpr int LA = BM / 32, LB = BN / 32;   // 16B loads / thread / 64-k panel
    constexpr int LL = LA + LB;
    constexpr int APAN = BM * 64, BPAN = BN * 64;   // f16 per 64-k panel
    constexpr int NB = 4;
    __shared__ _Float16 smem[NB * (APAN + BPAN)];
    const int tid = threadIdx.x;

    // ---- XCD-aware bijective block swizzle (m204) ----
    const int gx = gridDim.x, gy = gridDim.y;
    const int nwg = gx * gy * (int)gridDim.z;
    const int orig = ((int)blockIdx.z * gy + (int)blockIdx.y) * gx + (int)blockIdx.x;
    const int xcd = orig & 7, loc = orig >> 3;
    const int q8 = nwg >> 3, r8 = nwg & 7;
    const int lid = (xcd < r8 ? xcd * (q8 + 1) : r8 * (q8 + 1) + (xcd - r8) * q8) + loc;
    const int bxi = lid % gx;
    const int rem = lid / gx;
    const int byi = rem % gy;
    const int z = rem / gy;

    const int K = g.K;
    const int m0 = byi * BM, n0 = bxi * BN;
    const _Float16* Ab = g.A + (long)z * g.bsA + (long)m0 * K;
    const _Float16* Bb = g.Bt + (long)z * g.bsB + (long)n0 * K;
    const int wave = tid >> 6, lane = tid & 63;
    const int wr = wave >> 1, wc = wave & 1;
    const int fr = lane & 15, kq = lane >> 4;
    const int srow = tid >> 3;             // 0..31 (row within 32-row load chunk)
    const int sc8 = (((tid & 7) ^ (srow & 7)) << 3);  // pre-swizzled 16B slot -> f16 col
    f32x4 acc[FA][FB] = {};

    auto stage = [&](int q, int kk) {
#pragma unroll
        for (int r = 0; r < LA; ++r)
            async_cp16(Ab + (long)(r * 32 + srow) * K + kk + sc8,
                       &smem[q * APAN + r * 2048 + wave * 512]);
#pragma unroll
        for (int r = 0; r < LB; ++r)
            async_cp16(Bb + (long)(r * 32 + srow) * K + kk + sc8,
                       &smem[NB * APAN + q * BPAN + r * 2048 + wave * 512]);
    };

    // logical 16B slot for (h,kq) is h*4+kq; swizzled slot = (h*4+kq) ^ (row&7),
    // row&7 == fr&7 for all fragments (wr*WM, wc*WN, i*16 are multiples of 8)
    const int sl0 = ((kq ^ (fr & 7)) << 3);        // h=0 f16 col offset
    const int sl1 = (((4 + kq) ^ (fr & 7)) << 3);  // h=1 f16 col offset

    auto compute = [&](int q) {
        f16x8 af[2][FA], bf[2][FB];
        const int abase = q * APAN;
#pragma unroll
        for (int i = 0; i < FA; ++i) {
            const int ro = (wr * WM + i * 16 + fr) * 64;
            af[0][i] = *(const f16x8*)&smem[abase + ro + sl0];
            af[1][i] = *(const f16x8*)&smem[abase + ro + sl1];
        }
        const int bbase = NB * APAN + q * BPAN;
#pragma unroll
        for (int j = 0; j < FB; ++j) {
            const int ro = (wc * WN + j * 16 + fr) * 64;
            bf[0][j] = *(const f16x8*)&smem[bbase + ro + sl0];
            bf[1][j] = *(const f16x8*)&smem[bbase + ro + sl1];
        }
        __builtin_amdgcn_s_setprio(1);
#pragma unroll
        for (int h = 0; h < 2; ++h)
#pragma unroll
            for (int i = 0; i < FA; ++i)
#pragma unroll
                for (int j = 0; j < FB; ++j)
                    acc[i][j] = __builtin_amdgcn_mfma_f32_16x16x32_f16(af[h][i], bf[h][j], acc[i][j], 0, 0, 0);
        __builtin_amdgcn_s_setprio(0);
    };

    const int nk = K >> 6;                 // 64-k panels (>= 3)
    stage(0, 0); stage(1, 64); stage(2, 128);
    int qc = 0, qs = 3;
    for (int t = 0; t < nk; ++t) {
        if (t + 2 < nk)      waitvm<2 * LL>();   // panel t landed; t+1,t+2 in flight
        else if (t + 1 < nk) waitvm<LL>();
        else                 waitvm<0>();
        BARRIER();                          // panel t ready; slot qs free
        if (t + 3 < nk) stage(qs, (t + 3) << 6);
        compute(qc);
        qc = (qc + 1) & 3;
        qs = (qs + 1) & 3;
    }

    // ---- finalize values in acc ----
#pragma unroll
    for (int i = 0; i < FA; ++i) {
        const int gm0 = m0 + wr * WM + i * 16 + kq * 4;
#pragma unroll
        for (int j = 0; j < FB; ++j) {
            const int gn = n0 + wc * WN + j * 16 + fr;
            if (gn >= g.N) continue;
            if (g.act == 4) {
                const int seg = gn >> 10, gl = gn & 1023;
#pragma unroll
                for (int r = 0; r < 4; ++r) {
                    const int gm = gm0 + r;
                    if (gm >= g.M) continue;
                    const float v = acc[i][j][r];
                    if (seg == 0) g.Ch[(long)gm * 1024 + gl] = (_Float16)v;
                    else if (seg == 1) g.Cf[(long)gm * 1024 + gl] = v;
                    else g.Cf2[(long)gm * 1024 + gl] = v;
                }
            } else {
                const float bv = g.bias ? g.bias[gn] : 0.f;
#pragma unroll
                for (int r = 0; r < 4; ++r) {
                    const int gm = gm0 + r;
                    if (gm >= g.M) continue;
                    const float raw = acc[i][j][r] + bv;
                    float av = raw;
                    if (g.act == 1) av = raw / (1.f + __expf(-raw));
                    else if (g.act == 2) {
                        const float a = g.aux[(long)z * g.bsX + (long)gm * g.ldx + gn];
                        const float s = 1.f / (1.f + __expf(-a));
                        av = raw * (s * (1.f + a * (1.f - s)));
                    }
                    float v = g.s1 * av;
                    if (g.resid) v += g.s2 * g.resid[(long)z * g.bsR + (long)gm * g.ldr + gn];
                    if (g.Cf) g.Cf[(long)z * g.bsC + (long)gm * g.ldc + gn] = (g.act == 1) ? raw : v;
                    if (g.Ch) g.Ch[(long)z * g.bsH + (long)gm * g.ldh + gn] = (_Float16)v;
                    acc[i][j][r] = v;
                }
            }
        }
    }

    // ---- coalesced transposed store via LDS ----
    if (g.Ct && (g.act != 4 || n0 < 1024)) {
        constexpr int TP = BM + 8;
        __syncthreads();
#pragma unroll
        for (int i = 0; i < FA; ++i) {
            const int lm = wr * WM + i * 16 + kq * 4;
#pragma unroll
            for (int j = 0; j < FB; ++j) {
                const int ln = wc * WN + j * 16 + fr;
#pragma unroll
                for (int r = 0; r < 4; ++r)
                    smem[ln * TP + lm + r] = (_Float16)acc[i][j][r];
            }
        }
        __syncthreads();
        constexpr int TPC = 256 / BN;       // threads per output column
        constexpr int SEG = BM / TPC;       // rows stored per thread
        const int ln = tid / TPC, part = tid % TPC;
        const int gn = n0 + ln;
        if (gn < g.N) {
            const int gmb = m0 + part * SEG;
            _Float16* dst = g.Ct + (long)z * g.bsT + (long)gn * g.ldt + gmb;
            const _Float16* src = &smem[ln * TP + part * SEG];
#pragma unroll
            for (int gi = 0; gi < SEG / 8; ++gi)
                if (gmb + gi * 8 < g.M)
                    *(uint4*)(dst + gi * 8) = *(const uint4*)(src + gi * 8);
        }
    }
}

// ---- fused momentum + weight update + f16 cast + transpose ----
// blocks 0..511: w1 (R=2048,C=1024) -> mom1,w1m RMW, w1row f16, w1T f16 [1024][2048]
// blocks 512..1023: w0 (R=1024,C=2048) -> mom0,w0m RMW, w0T f16 [2048][1024]
__global__ void momupT_k(const float* __restrict__ dW1, float* __restrict__ mom1,
                         float* __restrict__ w1m, _Float16* __restrict__ w1row,
                         _Float16* __restrict__ w1t,
                         const float* __restrict__ dW0, float* __restrict__ mom0,
                         float* __restrict__ w0m, _Float16* __restrict__ w0t)
{
    __shared__ _Float16 t[64][65];
    const int b = blockIdx.x;
    const int tid = threadIdx.x;
    const float* dW; float* mom; float* wm; _Float16* wrow; _Float16* wT;
    int C, RT, r0, c0;
    if (b < 512) {
        dW = dW1; mom = mom1; wm = w1m; wrow = w1row; wT = w1t;
        C = 1024; RT = 2048;
        r0 = (b >> 4) << 6; c0 = (b & 15) << 6;
    } else {
        const int bb = b - 512;
        dW = dW0; mom = mom0; wm = w0m; wrow = nullptr; wT = w0t;
        C = 2048; RT = 1024;
        r0 = (bb >> 5) << 6; c0 = (bb & 31) << 6;
    }
#pragma unroll
    for (int i = 0; i < 4; ++i) {
        const int f = i * 256 + tid;
        const int rr = f >> 4;              // 0..63
        const int c4 = (f & 15) << 2;       // 0..60
        const long idx = (long)(r0 + rr) * C + c0 + c4;
        const float4 d = *(const float4*)(dW + idx);
        float4 mo = *(const float4*)(mom + idx);
        float4 w  = *(const float4*)(wm + idx);
        mo.x = 0.9f * mo.x + d.x; mo.y = 0.9f * mo.y + d.y;
        mo.z = 0.9f * mo.z + d.z; mo.w = 0.9f * mo.w + d.w;
        w.x = 0.99f * w.x - 0.01f * mo.x; w.y = 0.99f * w.y - 0.01f * mo.y;
        w.z = 0.99f * w.z - 0.01f * mo.z; w.w = 0.99f * w.w - 0.01f * mo.w;
        *(float4*)(mom + idx) = mo;
        *(float4*)(wm + idx) = w;
        const _Float16 h0 = (_Float16)w.x, h1 = (_Float16)w.y,
                       h2 = (_Float16)w.z, h3 = (_Float16)w.w;
        if (wrow) {
            wrow[idx] = h0; wrow[idx + 1] = h1;
            wrow[idx + 2] = h2; wrow[idx + 3] = h3;
        }
        t[rr][c4] = h0; t[rr][c4 + 1] = h1; t[rr][c4 + 2] = h2; t[rr][c4 + 3] = h3;
    }
    __syncthreads();
#pragma unroll
    for (int i = 0; i < 4; ++i) {
        const int f = i * 256 + tid;
        const int cc = f >> 4;              // tile col (output row)
        const int rr4 = (f & 15) << 2;      // tile rows, 4 consecutive
        ushort4 u;
        u.x = *(const unsigned short*)&t[rr4][cc];
        u.y = *(const unsigned short*)&t[rr4 + 1][cc];
        u.z = *(const unsigned short*)&t[rr4 + 2][cc];
        u.w = *(const unsigned short*)&t[rr4 + 3][cc];
        *(ushort4*)(wT + (long)(c0 + cc) * RT + r0 + rr4) = u;
    }
}

// ---- elementwise / rowwise ----
__global__ void cvt_k(const float* __restrict__ in, _Float16* __restrict__ out, long n)
{
    long i = ((long)blockIdx.x * 256 + threadIdx.x) * 4;
    if (i >= n) return;
    const float4 v = *(const float4*)(in + i);
    out[i] = (_Float16)v.x; out[i + 1] = (_Float16)v.y;
    out[i + 2] = (_Float16)v.z; out[i + 3] = (_Float16)v.w;
}

__global__ void cvtT_k(const float* __restrict__ in, _Float16* __restrict__ out, int R, int C)
{
    __shared__ _Float16 t[64][65];
    const int c0 = blockIdx.x * 64, r0 = blockIdx.y * 64;
    const int tid = threadIdx.x;
    for (int i = 0; i < 16; ++i) {
        const int lin = i * 256 + tid;
        const int r = lin >> 6, cc = lin & 63;
        t[r][cc] = (_Float16)in[(long)(r0 + r) * C + c0 + cc];
    }
    __syncthreads();
    for (int i = 0; i < 16; ++i) {
        const int lin = i * 256 + tid;
        const int r2 = lin >> 6, c2 = lin & 63;
        out[(long)(c0 + r2) * R + r0 + c2] = t[c2][r2];
    }
}

__global__ void l2n16s_k(const float* __restrict__ in, long ld,
                         _Float16* __restrict__ out, float scale)
{
    const long row = blockIdx.x;
    const float* p = in + row * ld;
    _Float16* q = out + row * DD;
    const int t = threadIdx.x;
    float e0 = p[t], e1 = p[t + 256], e2 = p[t + 512], e3 = p[t + 768];
    __shared__ float rq[256];
    rq[t] = e0 * e0 + e1 * e1 + e2 * e2 + e3 * e3;
    __syncthreads();
    for (int k = 128; k; k >>= 1) { if (t < k) rq[t] += rq[t + k]; __syncthreads(); }
    const float f = scale / fmaxf(sqrtf(rq[0]), 1e-12f);
    q[t] = (_Float16)(e0 * f); q[t + 256] = (_Float16)(e1 * f);
    q[t + 512] = (_Float16)(e2 * f); q[t + 768] = (_Float16)(e3 * f);
}

// fused q + k l2norm from F32QK [2080][2048]
__global__ void l2qk_k(const float* __restrict__ qk, _Float16* __restrict__ q16,
                       _Float16* __restrict__ k16)
{
    const int blk = blockIdx.x;     // 0..3103
    const float* p; _Float16* o; float scale;
    if (blk < 1024) {
        const int b = blk >> 9, r = blk & 511;
        p = qk + (long)(b * SB + PPc + CC + r) * 2048;
        o = q16 + (long)blk * DD; scale = 32.f;
    } else {
        const int row = blk - 1024;
        p = qk + (long)row * 2048 + 1024;
        o = k16 + (long)row * DD; scale = 1.f;
    }
    const int t = threadIdx.x;
    float e0 = p[t], e1 = p[t + 256], e2 = p[t + 512], e3 = p[t + 768];
    __shared__ float rq[256];
    rq[t] = e0 * e0 + e1 * e1 + e2 * e2 + e3 * e3;
    __syncthreads();
    for (int k = 128; k; k >>= 1) { if (t < k) rq[t] += rq[t + k]; __syncthreads(); }
    const float f = scale / fmaxf(sqrtf(rq[0]), 1e-12f);
    o[t] = (_Float16)(e0 * f); o[t + 256] = (_Float16)(e1 * f);
    o[t + 512] = (_Float16)(e2 * f); o[t + 768] = (_Float16)(e3 * f);
}

__global__ void lnaug_k(const float* __restrict__ x, const float* __restrict__ pers,
                        const float* __restrict__ h, const float* __restrict__ g,
                        const float* __restrict__ b, _Float16* __restrict__ out, int c)
{
    const int row = blockIdx.x;             // 0..2079
    const int bb = row / SB, i = row % SB;
    const float* p;
    if (i < PPc) p = pers + (long)i * DD;
    else if (i < PPc + CC) p = h + (long)(bb * CC + i - PPc) * DD;
    else p = x + (long)(bb * TT + c * CC + (i - PPc - CC)) * DD;
    _Float16* q = out + (long)row * DD;
    const int t = threadIdx.x;
    float e0 = p[t], e1 = p[t + 256], e2 = p[t + 512], e3 = p[t + 768];
    __shared__ float rs[256], rq[256];
    rs[t] = e0 + e1 + e2 + e3;
    rq[t] = e0 * e0 + e1 * e1 + e2 * e2 + e3 * e3;
    __syncthreads();
    for (int k = 128; k; k >>= 1) {
        if (t < k) { rs[t] += rs[t + k]; rq[t] += rq[t + k]; }
        __syncthreads();
    }
    const float mean = rs[0] * (1.f / DD);
    const float inv = rsqrtf(rq[0] * (1.f / DD) - mean * mean + 1e-5f);
    q[t]       = (_Float16)((e0 - mean) * inv * g[t]       + b[t]);
    q[t + 256] = (_Float16)((e1 - mean) * inv * g[t + 256] + b[t + 256]);
    q[t + 512] = (_Float16)((e2 - mean) * inv * g[t + 512] + b[t + 512]);
    q[t + 768] = (_Float16)((e3 - mean) * inv * g[t + 768] + b[t + 768]);
}

__global__ void softmax16_k(const float* __restrict__ sc, _Float16* __restrict__ pr)
{
    const int blk = blockIdx.x;             // 0..1023
    const int r = blk & 511;
    const int i = PPc + CC + r;
    const float* p = sc + (long)blk * SB;
    _Float16* q = pr + (long)blk * KA;
    const int t = threadIdx.x;
    __shared__ float red[256];
    float mx = -3.0e38f;
    for (int j = t; j < SB; j += 256)
        if (j <= i) mx = fmaxf(mx, p[j]);
    red[t] = mx; __syncthreads();
    for (int k = 128; k; k >>= 1) { if (t < k) red[t] = fmaxf(red[t], red[t + k]); __syncthreads(); }
    mx = red[0]; __syncthreads();
    float sum = 0.f;
    for (int j = t; j < SB; j += 256)
        if (j <= i) sum += __expf(p[j] - mx);
    red[t] = sum; __syncthreads();
    for (int k = 128; k; k >>= 1) { if (t < k) red[t] += red[t + k]; __syncthreads(); }
    const float inv = 1.f / red[0];
    for (int j = t; j < KA; j += 256) {
        float e = 0.f;
        if (j < SB && j <= i) e = __expf(p[j] - mx) * inv;
        q[j] = (_Float16)e;
    }
}

__global__ void gateln2_k(const float* __restrict__ yt, const float* __restrict__ gp,
                          const float* __restrict__ mo, const float* __restrict__ g,
                          const float* __restrict__ b, float* __restrict__ OF,
                          _Float16* __restrict__ o16)
{
    const long row = blockIdx.x;
    const int t = threadIdx.x;
    float e[4];
    __shared__ float rs[256], rq[256];
    float ssum = 0.f, qsum = 0.f;
#pragma unroll
    for (int k = 0; k < 4; ++k) {
        const long idx = row * DD + t + k * 256;
        const float s = 1.f / (1.f + __expf(-gp[idx]));
        e[k] = yt[idx] * s + mo[idx] * (1.f - s);
        OF[idx] = e[k];
        ssum += e[k]; qsum += e[k] * e[k];
    }
    rs[t] = ssum; rq[t] = qsum;
    __syncthreads();
    for (int k = 128; k; k >>= 1) {
        if (t < k) { rs[t] += rs[t + k]; rq[t] += rq[t + k]; }
        __syncthreads();
    }
    const float mean = rs[0] * (1.f / DD);
    const float inv = rsqrtf(rq[0] * (1.f / DD) - mean * mean + 1e-5f);
#pragma unroll
    for (int k = 0; k < 4; ++k) {
        const int cc = t + k * 256;
        o16[row * DD + cc] = (_Float16)((e[k] - mean) * inv * g[cc] + b[cc]);
    }
}

// fused tail: blocks 0..3071 rowsum + bias momentum update (rT16->mb1, da0T->mb0);
// 3072..4095 l2norm(F32A row)->qm16; 4096..5119 LN(YTF row)->gl16
__global__ void tailfuse_k(const _Float16* __restrict__ rT, const _Float16* __restrict__ daT,
                           float* __restrict__ mb0, float* __restrict__ mob0,
                           float* __restrict__ mb1, float* __restrict__ mob1,
                           const float* __restrict__ qmp, _Float16* __restrict__ qm16,
                           const float* __restrict__ ytf, const float* __restrict__ gg,
                           const float* __restrict__ gb, _Float16* __restrict__ gl)
{
    const int blk = blockIdx.x;
    const int t = threadIdx.x;
    __shared__ float rs[256], rq[256];
    if (blk < 3072) {
        const _Float16* p = (blk < 1024) ? rT + (long)blk * 1024
                                         : daT + (long)(blk - 1024) * 1024;
        rs[t] = (float)p[t] + (float)p[t + 256] + (float)p[t + 512] + (float)p[t + 768];
        __syncthreads();
        for (int k = 128; k; k >>= 1) { if (t < k) rs[t] += rs[t + k]; __syncthreads(); }
        if (t == 0) {
            const float d = rs[0];
            if (blk < 1024) {
                const float m = 0.9f * mob1[blk] + d;
                mob1[blk] = m;
                mb1[blk] = 0.99f * mb1[blk] - 0.01f * m;
            } else {
                const int j = blk - 1024;
                const float m = 0.9f * mob0[j] + d;
                mob0[j] = m;
                mb0[j] = 0.99f * mb0[j] - 0.01f * m;
            }
        }
    } else if (blk < 4096) {
        const long row = blk - 3072;
        const float* p = qmp + row * DD;
        _Float16* q = qm16 + row * DD;
        float e0 = p[t], e1 = p[t + 256], e2 = p[t + 512], e3 = p[t + 768];
        rq[t] = e0 * e0 + e1 * e1 + e2 * e2 + e3 * e3;
        __syncthreads();
        for (int k = 128; k; k >>= 1) { if (t < k) rq[t] += rq[t + k]; __syncthreads(); }
        const float f = 1.f / fmaxf(sqrtf(rq[0]), 1e-12f);
        q[t] = (_Float16)(e0 * f); q[t + 256] = (_Float16)(e1 * f);
        q[t + 512] = (_Float16)(e2 * f); q[t + 768] = (_Float16)(e3 * f);
    } else {
        const long row = blk - 4096;
        const float* p = ytf + row * DD;
        _Float16* q = gl + row * DD;
        float e0 = p[t], e1 = p[t + 256], e2 = p[t + 512], e3 = p[t + 768];
        rs[t] = e0 + e1 + e2 + e3;
        rq[t] = e0 * e0 + e1 * e1 + e2 * e2 + e3 * e3;
        __syncthreads();
        for (int k = 128; k; k >>= 1) {
            if (t < k) { rs[t] += rs[t + k]; rq[t] += rq[t + k]; }
            __syncthreads();
        }
        const float mean = rs[0] * (1.f / DD);
        const float inv = rsqrtf(rq[0] * (1.f / DD) - mean * mean + 1e-5f);
        q[t]       = (_Float16)((e0 - mean) * inv * gg[t]       + gb[t]);
        q[t + 256] = (_Float16)((e1 - mean) * inv * gg[t + 256] + gb[t + 256]);
        q[t + 512] = (_Float16)((e2 - mean) * inv * gg[t + 512] + gb[t + 512]);
        q[t + 768] = (_Float16)((e3 - mean) * inv * gg[t + 768] + gb[t + 768]);
    }
}

__global__ void zero_k(float* __restrict__ p, long n)
{
    long i = (long)blockIdx.x * 256 + threadIdx.x;
    const long st = (long)gridDim.x * 256;
    for (; i < n; i += st) p[i] = 0.f;
}

extern "C" void kernel_launch(void* const* d_in, const int* in_sizes, int n_in,
                              void* d_out, int out_size, void* d_ws, size_t ws_size,
                              hipStream_t stream)
{
    const float* x          = (const float*)d_in[0];
    const float* wq_ctx     = (const float*)d_in[1];
    const float* wq         = (const float*)d_in[2];
    const float* wk         = (const float*)d_in[3];
    const float* wv         = (const float*)d_in[4];
    const float* w_attn_out = (const float*)d_in[5];
    const float* w_gate     = (const float*)d_in[6];
    const float* gate_g     = (const float*)d_in[7];
    const float* gate_b     = (const float*)d_in[8];
    const float* n1_g       = (const float*)d_in[9];
    const float* n1_b       = (const float*)d_in[10];
    const float* n2_g       = (const float*)d_in[11];
    const float* n2_b       = (const float*)d_in[12];
    const float* ffn_w1     = (const float*)d_in[13];
    const float* ffn_b1     = (const float*)d_in[14];
    const float* ffn_w2     = (const float*)d_in[15];
    const float* ffn_b2     = (const float*)d_in[16];
    const float* pers       = (const float*)d_in[17];
    const float* mem_w0_in  = (const float*)d_in[18];
    const float* mem_b0_in  = (const float*)d_in[19];
    const float* mem_w1_in  = (const float*)d_in[20];
    const float* mem_b1_in  = (const float*)d_in[21];
    const float* mem_wk     = (const float*)d_in[22];
    const float* mem_wv     = (const float*)d_in[23];
    float* out = (float*)d_out;
    (void)in_sizes; (void)n_in; (void)out_size; (void)ws_size;

    char* cur = (char*)d_ws;
    auto allocF = [&](size_t n) { float* p = (float*)cur; cur += n * 4; return p; };
    auto allocH = [&](size_t n) { _Float16* p = (_Float16*)cur; cur += n * 2; return p; };

    float* mw0   = allocF((size_t)DD * HH);
    float* mw1   = allocF((size_t)HH * DD);
    float* mb0   = allocF(HH);
    float* mb1   = allocF(DD);
    float* mom   = allocF((size_t)DD * HH * 2 + HH + DD);
    float* mom_w0 = mom, *mom_w1 = mom + (size_t)DD * HH;
    float* mom_b0 = mom_w1 + (size_t)HH * DD, *mom_b1 = mom_b0 + HH;
    float* F32A  = allocF((size_t)1024 * DD);
    float* F32B  = allocF((size_t)1024 * DD);
    float* F32C  = allocF((size_t)1024 * HH);
    float* F32QK = allocF((size_t)2112 * 2048);
    float* YTF   = allocF((size_t)1024 * DD);
    float* OF    = allocF((size_t)1024 * DD);

    _Float16* x16    = allocH((size_t)2 * TT * DD);
    _Float16* wqcT   = allocH((size_t)DD * DD);
    _Float16* wqkT   = allocH((size_t)2048 * DD);
    _Float16* wvT    = allocH((size_t)DD * DD);
    _Float16* waoT   = allocH((size_t)DD * DD);
    _Float16* wgT    = allocH((size_t)DD * DD);
    _Float16* wmixT  = allocH((size_t)3072 * DD);
    _Float16* f1T    = allocH((size_t)FFd * DD);
    _Float16* f2T    = allocH((size_t)DD * FFd);
    _Float16* w0T    = allocH((size_t)HH * DD);
    _Float16* w1T    = allocH((size_t)DD * HH);
    _Float16* w1p    = allocH((size_t)HH * DD);
    _Float16* xn16   = allocH((size_t)1024 * DD);
    _Float16* h116   = allocH((size_t)1024 * HH);
    _Float16* laug16 = allocH((size_t)2208 * DD);
    _Float16* q16    = allocH((size_t)1024 * DD);
    _Float16* k16    = allocH((size_t)2208 * DD);
    _Float16* vT16   = allocH((size_t)2 * DD * KA);
    _Float16* pr16   = allocH((size_t)2 * 512 * KA);
    _Float16* ao16   = allocH((size_t)1024 * DD);
    _Float16* yt16   = allocH((size_t)1024 * DD);
    _Float16* kk16   = allocH((size_t)1024 * DD);
    _Float16* kkT16  = allocH((size_t)DD * 1024);
    _Float16* hs16   = allocH((size_t)1024 * HH);
    _Float16* hsT16  = allocH((size_t)HH * 1024);
    _Float16* r16    = allocH((size_t)1024 * DD);
    _Float16* rT16   = allocH((size_t)DD * 1024);
    _Float16* da0T   = allocH((size_t)HH * 1024);
    _Float16* qm16   = allocH((size_t)1024 * DD);
    _Float16* a216   = allocH((size_t)1024 * HH);
    _Float16* gl16   = allocH((size_t)1024 * DD);
    _Float16* h216   = allocH((size_t)1024 * DD);
    _Float16* f116   = allocH((size_t)1024 * FFd);

    auto launch = [&](int nz, const GP& g) {
        dim3 grid((g.N + 63) / 64, (g.M + 63) / 64, nz);
        gemm16<64, 64><<<grid, 256, 0, stream>>>(g);
    };

    // ---- init ----
    hipMemcpyAsync(mw0, mem_w0_in, sizeof(float) * DD * HH, hipMemcpyDeviceToDevice, stream);
    hipMemcpyAsync(mw1, mem_w1_in, sizeof(float) * HH * DD, hipMemcpyDeviceToDevice, stream);
    hipMemcpyAsync(mb0, mem_b0_in, sizeof(float) * HH, hipMemcpyDeviceToDevice, stream);
    hipMemcpyAsync(mb1, mem_b1_in, sizeof(float) * DD, hipMemcpyDeviceToDevice, stream);
    zero_k<<<4096, 256, 0, stream>>>(mom, (long)DD * HH * 2 + HH + DD);
    cvt_k<<<(2 * TT * DD) / 1024, 256, 0, stream>>>(x, x16, (long)2 * TT * DD);
    auto T64 = [&](const float* in, _Float16* o, int R, int C) {
        cvtT_k<<<dim3(C / 64, R / 64), 256, 0, stream>>>(in, o, R, C);
    };
    T64(wq_ctx, wqcT, DD, DD);
    T64(wq, wqkT, DD, DD); T64(wk, wqkT + (size_t)1024 * DD, DD, DD);
    T64(wv, wvT, DD, DD); T64(w_attn_out, waoT, DD, DD); T64(w_gate, wgT, DD, DD);
    T64(mem_wk, wmixT, DD, DD); T64(mem_wv, wmixT + (size_t)1024 * DD, DD, DD);
    T64(wq_ctx, wmixT + (size_t)2048 * DD, DD, DD);
    T64(ffn_w1, f1T, DD, FFd); T64(ffn_w2, f2T, FFd, DD);
    T64(mem_w0_in, w0T, DD, HH); T64(mem_w1_in, w1T, HH, DD);
    cvt_k<<<(HH * DD) / 1024, 256, 0, stream>>>(mem_w1_in, w1p, (long)HH * DD);

    for (int c = 0; c < NCH; ++c) {
        GP g;
        // 1. xn_pre = seg @ wq_ctx  (z=2)
        g = GP{}; g.A = x16 + (long)c * CC * DD; g.bsA = (long)TT * DD; g.Bt = wqcT;
        g.Cf = F32A; g.ldc = DD; g.bsC = (long)CC * DD;
        g.s1 = 1.f; g.M = CC; g.N = DD; g.K = DD;
        launch(2, g);
        l2n16s_k<<<1024, 256, 0, stream>>>(F32A, DD, xn16, 1.f);
        // 2. h = mem_mlp(mem, xn)
        g = GP{}; g.A = xn16; g.Bt = w0T; g.bias = mb0; g.Ch = h116; g.ldh = HH;
        g.s1 = 1.f; g.M = 1024; g.N = HH; g.K = DD; g.act = 1;
        launch(1, g);
        g = GP{}; g.A = h116; g.Bt = w1T; g.bias = mb1; g.Cf = F32B; g.ldc = DD;
        g.s1 = 1.f; g.M = 1024; g.N = DD; g.K = HH;
        launch(1, g);
        lnaug_k<<<2 * SB, 256, 0, stream>>>(x, pers, F32B, n1_g, n1_b, laug16, c);
        // 3. q|k fused
        g = GP{}; g.A = laug16; g.Bt = wqkT; g.Cf = F32QK; g.ldc = 2048;
        g.s1 = 1.f; g.M = 2 * SB; g.N = 2048; g.K = DD;
        launch(1, g);
        l2qk_k<<<3104, 256, 0, stream>>>(F32QK, q16, k16);
        // 4. v (transposed out)
        g = GP{}; g.A = laug16; g.bsA = (long)SB * DD; g.Bt = wvT;
        g.Ct = vT16; g.ldt = KA; g.bsT = (long)DD * KA;
        g.s1 = 1.f; g.M = SB; g.N = DD; g.K = DD;
        launch(2, g);
        // 5. scores + softmax + PV
        g = GP{}; g.A = q16; g.bsA = (long)512 * DD; g.Bt = k16; g.bsB = (long)SB * DD;
        g.Cf = F32C; g.ldc = SB; g.bsC = (long)512 * SB;
        g.s1 = 1.f; g.M = 512; g.N = SB; g.K = DD;
        launch(2, g);
        softmax16_k<<<1024, 256, 0, stream>>>(F32C, pr16);
        g = GP{}; g.A = pr16; g.bsA = (long)512 * KA; g.Bt = vT16; g.bsB = (long)DD * KA;
        g.Ch = ao16; g.ldh = DD; g.bsH = (long)512 * DD;
        g.s1 = 1.f; g.M = 512; g.N = DD; g.K = KA;
        launch(2, g);
        // 6. y_t = seg + attn @ wao
        g = GP{}; g.A = ao16; g.bsA = (long)512 * DD; g.Bt = waoT;
        g.resid = x + (long)c * CC * DD; g.ldr = DD; g.bsR = (long)TT * DD;
        g.Cf = YTF; g.ldc = DD; g.bsC = (long)512 * DD;
        g.Ch = yt16; g.ldh = DD; g.bsH = (long)512 * DD;
        g.s1 = 1.f; g.s2 = 1.f; g.M = 512; g.N = DD; g.K = DD;
        launch(2, g);
        // 7. kk | vv | qm_pre fused (act 4) with kkT via LDS transpose
        g = GP{}; g.A = yt16; g.Bt = wmixT; g.Ch = kk16; g.Ct = kkT16; g.ldt = 1024;
        g.Cf = F32B; g.Cf2 = F32A;
        g.s1 = 1.f; g.M = 1024; g.N = 3072; g.K = DD; g.act = 4;
        launch(1, g);
        // 8. a0 = kk@w0+b0 (raw) ; hs/hsT = silu
        g = GP{}; g.A = kk16; g.Bt = w0T; g.bias = mb0; g.Cf = F32C; g.ldc = HH;
        g.Ch = hs16; g.ldh = HH; g.Ct = hsT16; g.ldt = 1024;
        g.s1 = 1.f; g.M = 1024; g.N = HH; g.K = DD; g.act = 1;
        launch(1, g);
        // 9. r = (hs@w1 + b1 - vv)/1024
        g = GP{}; g.A = hs16; g.Bt = w1T; g.bias = mb1;
        g.resid = F32B; g.ldr = DD;
        g.Ch = r16; g.ldh = DD; g.Ct = rT16; g.ldt = 1024;
        g.s1 = 1.f / 1024.f; g.s2 = -1.f / 1024.f; g.M = 1024; g.N = DD; g.K = HH;
        launch(1, g);
        // 10. da0T = (r @ w1_old^T) * dsilu(a0)   (before w1 update!)
        g = GP{}; g.A = r16; g.Bt = w1p; g.aux = F32C; g.ldx = HH;
        g.Ct = da0T; g.ldt = 1024;
        g.s1 = 1.f; g.M = 1024; g.N = HH; g.K = DD; g.act = 2;
        launch(1, g);
        // fused tail: rowsums + bias momentum update | l2norm(qm_pre) | LN(YTF)
        tailfuse_k<<<5120, 256, 0, stream>>>(rT16, da0T, mb0, mom_b0, mb1, mom_b1,
                                             F32A, qm16, YTF, gate_g, gate_b, gl16);
        // 11a. dW1 = hsT @ rT (plain GEMM, f32 -> F32C; F32C free after step 10)
        g = GP{}; g.A = hsT16; g.Bt = rT16; g.Cf = F32C; g.ldc = DD;
        g.s1 = 1.f; g.M = HH; g.N = DD; g.K = 1024;
        launch(1, g);
        // 11b. dW0 = kkT @ da0T (plain GEMM, f32 -> F32QK; free after l2qk)
        g = GP{}; g.A = kkT16; g.Bt = da0T; g.Cf = F32QK; g.ldc = HH;
        g.s1 = 1.f; g.M = DD; g.N = HH; g.K = 1024;
        launch(1, g);
        // 11c. fused momentum + weight update + f16 cast + transpose (both weights)
        momupT_k<<<1024, 256, 0, stream>>>(F32C, mom_w1, mw1, w1p, w1T,
                                           F32QK, mom_w0, mw0, w0T);
        // 13. mem_out = mem_mlp(new mem, qm16)
        g = GP{}; g.A = qm16; g.Bt = w0T; g.bias = mb0; g.Ch = a216; g.ldh = HH;
        g.s1 = 1.f; g.M = 1024; g.N = HH; g.K = DD; g.act = 1;
        launch(1, g);
        g = GP{}; g.A = a216; g.Bt = w1T; g.bias = mb1; g.Cf = F32B; g.ldc = DD;
        g.s1 = 1.f; g.M = 1024; g.N = DD; g.K = HH;
        launch(1, g);
        // 14. gate projection (gl16 from tailfuse)
        g = GP{}; g.A = gl16; g.Bt = wgT; g.Cf = F32C; g.ldc = DD;
        g.s1 = 1.f; g.M = 1024; g.N = DD; g.K = DD;
        launch(1, g);
        gateln2_k<<<1024, 256, 0, stream>>>(YTF, F32C, F32B, n2_g, n2_b, OF, h216);
        // 15. FFN
        g = GP{}; g.A = h216; g.Bt = f1T; g.bias = ffn_b1; g.Ch = f116; g.ldh = FFd;
        g.s1 = 1.f; g.M = 1024; g.N = FFd; g.K = DD; g.act = 1;
        launch(1, g);
        g = GP{}; g.A = f116; g.bsA = (long)512 * FFd; g.Bt = f2T; g.bias = ffn_b2;
        g.resid = OF; g.ldr = DD; g.bsR = (long)512 * DD;
        g.Cf = out + (long)c * CC * DD; g.ldc = DD; g.bsC = (long)TT * DD;
        g.s1 = 1.f; g.s2 = 1.f; g.M = 512; g.N = DD; g.K = FFd;
        launch(2, g);
    }
}

// Round 10
// 3038.615 us; speedup vs baseline: 1.0770x; 1.0770x over previous
//
#include <hip/hip_runtime.h>

#define DD 1024
#define HH 2048
#define TT 4096
#define CC 512
#define PPc 16
#define SB 1040   // per-batch aug rows
#define KA 1088   // padded attention K (multiple of 64)
#define FFd 4096
#define NCH 8

typedef _Float16 f16x8 __attribute__((ext_vector_type(8)));
typedef float f32x4 __attribute__((ext_vector_type(4)));

typedef const __attribute__((address_space(1))) _Float16* gas_t;
typedef __attribute__((address_space(3))) _Float16* las_t;

__device__ __forceinline__ void async_cp16(const _Float16* g, _Float16* l) {
    __builtin_amdgcn_global_load_lds((gas_t)g, (las_t)l, 16, 0, 0);
}

template<int N> __device__ __forceinline__ void waitvm() {
    static_assert(N == 0 || N == 2 || N == 3 || N == 4 || N == 6 || N == 8, "unsupported vmcnt");
    if constexpr (N == 0)      asm volatile("s_waitcnt vmcnt(0)" ::: "memory");
    else if constexpr (N == 2) asm volatile("s_waitcnt vmcnt(2)" ::: "memory");
    else if constexpr (N == 3) asm volatile("s_waitcnt vmcnt(3)" ::: "memory");
    else if constexpr (N == 4) asm volatile("s_waitcnt vmcnt(4)" ::: "memory");
    else if constexpr (N == 6) asm volatile("s_waitcnt vmcnt(6)" ::: "memory");
    else                       asm volatile("s_waitcnt vmcnt(8)" ::: "memory");
}
#define BARRIER() asm volatile("s_barrier" ::: "memory")

struct GP {
    const _Float16* A; long bsA, ldA;
    const _Float16* Bt; long bsB, ldB;
    const float* bias;
    const float* resid; long ldr, bsR;
    const float* aux;   long ldx, bsX;
    float* Cf; long ldc, bsC;
    _Float16* Ch; long ldh, bsH;
    _Float16* Ct; long ldt, bsT;
    float* Mom;
    float* Cf2;
    float s1, s2;
    int M, N, K, act;
};

// acts: 0 plain, 1 silu (Cf<-raw, Ch/Ct<-silu*s1+resid), 2 mul-by-dsilu(aux),
//       4 routing (n<1024 -> Ch(+Ct), <2048 -> Cf, else Cf2; all ld 1024)
// K % 64 == 0, K >= 128. Ct GEMMs require M % 8 == 0.
// ldA/ldB are A/B row strides (= K normally; > K for split-K via z where
// z*bsA is a COLUMN offset into each row). NOTE: split-K GEMMs must NOT set
// bias (each half would add it) — bias is applied in the consumer kernel.
// Pipeline: 3 LDS buffers of 64-k panels, prefetch distance 2, counted vmcnt,
// raw s_barrier. LDS slots XOR-swizzled (T2): global source pre-swizzled so
// global_load_lds stays linear; ds_read applies the same involution.
template<int BM, int BN>
__global__ __launch_bounds__(256) void gemm16(GP g)
{
    constexpr int WM = BM / 2, WN = BN / 2;
    constexpr int FA = WM / 16, FB = WN / 16;
    constexpr int LA = BM / 32, LB = BN / 32;   // 16B loads / thread / 64-k panel
    constexpr int LL = LA + LB;
    constexpr int APAN = BM * 64, BPAN = BN * 64;   // f16 per 64-k panel
    constexpr int NB = 3;
    __shared__ _Float16 smem[NB * (APAN + BPAN)];
    const int tid = threadIdx.x;

    // ---- XCD-aware bijective block swizzle (m204) ----
    const int gx = gridDim.x, gy = gridDim.y;
    const int nwg = gx * gy * (int)gridDim.z;
    const int orig = ((int)blockIdx.z * gy + (int)blockIdx.y) * gx + (int)blockIdx.x;
    const int xcd = orig & 7, loc = orig >> 3;
    const int q8 = nwg >> 3, r8 = nwg & 7;
    const int lid = (xcd < r8 ? xcd * (q8 + 1) : r8 * (q8 + 1) + (xcd - r8) * q8) + loc;
    const int bxi = lid % gx;
    const int rem = lid / gx;
    const int byi = rem % gy;
    const int z = rem / gy;

    const int K = g.K;
    const long ldA = g.ldA, ldB = g.ldB;
    const int m0 = byi * BM, n0 = bxi * BN;
    const _Float16* Ab = g.A + (long)z * g.bsA + (long)m0 * ldA;
    const _Float16* Bb = g.Bt + (long)z * g.bsB + (long)n0 * ldB;
    const int wave = tid >> 6, lane = tid & 63;
    const int wr = wave >> 1, wc = wave & 1;
    const int fr = lane & 15, kq = lane >> 4;
    const int srow = tid >> 3;             // 0..31 (row within 32-row load chunk)
    const int sc8 = (((tid & 7) ^ (srow & 7)) << 3);  // pre-swizzled 16B slot -> f16 col
    f32x4 acc[FA][FB] = {};

    auto stage = [&](int q, int kk) {
#pragma unroll
        for (int r = 0; r < LA; ++r)
            async_cp16(Ab + (long)(r * 32 + srow) * ldA + kk + sc8,
                       &smem[q * APAN + r * 2048 + wave * 512]);
#pragma unroll
        for (int r = 0; r < LB; ++r)
            async_cp16(Bb + (long)(r * 32 + srow) * ldB + kk + sc8,
                       &smem[NB * APAN + q * BPAN + r * 2048 + wave * 512]);
    };

    // logical 16B slot for (h,kq) is h*4+kq; swizzled slot = (h*4+kq) ^ (row&7),
    // row&7 == fr&7 for all fragments (wr*WM, wc*WN, i*16 are multiples of 8)
    const int sl0 = ((kq ^ (fr & 7)) << 3);        // h=0 f16 col offset
    const int sl1 = (((4 + kq) ^ (fr & 7)) << 3);  // h=1 f16 col offset

    auto compute = [&](int q) {
        f16x8 af[2][FA], bf[2][FB];
        const int abase = q * APAN;
#pragma unroll
        for (int i = 0; i < FA; ++i) {
            const int ro = (wr * WM + i * 16 + fr) * 64;
            af[0][i] = *(const f16x8*)&smem[abase + ro + sl0];
            af[1][i] = *(const f16x8*)&smem[abase + ro + sl1];
        }
        const int bbase = NB * APAN + q * BPAN;
#pragma unroll
        for (int j = 0; j < FB; ++j) {
            const int ro = (wc * WN + j * 16 + fr) * 64;
            bf[0][j] = *(const f16x8*)&smem[bbase + ro + sl0];
            bf[1][j] = *(const f16x8*)&smem[bbase + ro + sl1];
        }
        __builtin_amdgcn_s_setprio(1);
#pragma unroll
        for (int h = 0; h < 2; ++h)
#pragma unroll
            for (int i = 0; i < FA; ++i)
#pragma unroll
                for (int j = 0; j < FB; ++j)
                    acc[i][j] = __builtin_amdgcn_mfma_f32_16x16x32_f16(af[h][i], bf[h][j], acc[i][j], 0, 0, 0);
        __builtin_amdgcn_s_setprio(0);
    };

    const int nk = K >> 6;                 // 64-k panels (>= 2)
    stage(0, 0); stage(1, 64);
    int qc = 0, qs = 2;
    for (int t = 0; t < nk; ++t) {
        if (t + 1 < nk) waitvm<LL>(); else waitvm<0>();
        BARRIER();                          // panel t ready; slot qs free
        if (t + 2 < nk) stage(qs, (t + 2) << 6);
        compute(qc);
        qc = (qc == NB - 1) ? 0 : qc + 1;
        qs = (qs == NB - 1) ? 0 : qs + 1;
    }

    // ---- finalize values in acc ----
#pragma unroll
    for (int i = 0; i < FA; ++i) {
        const int gm0 = m0 + wr * WM + i * 16 + kq * 4;
#pragma unroll
        for (int j = 0; j < FB; ++j) {
            const int gn = n0 + wc * WN + j * 16 + fr;
            if (gn >= g.N) continue;
            if (g.act == 4) {
                const int seg = gn >> 10, gl = gn & 1023;
#pragma unroll
                for (int r = 0; r < 4; ++r) {
                    const int gm = gm0 + r;
                    if (gm >= g.M) continue;
                    const float v = acc[i][j][r];
                    if (seg == 0) g.Ch[(long)gm * 1024 + gl] = (_Float16)v;
                    else if (seg == 1) g.Cf[(long)gm * 1024 + gl] = v;
                    else g.Cf2[(long)gm * 1024 + gl] = v;
                }
            } else {
                const float bv = g.bias ? g.bias[gn] : 0.f;
#pragma unroll
                for (int r = 0; r < 4; ++r) {
                    const int gm = gm0 + r;
                    if (gm >= g.M) continue;
                    const float raw = acc[i][j][r] + bv;
                    float av = raw;
                    if (g.act == 1) av = raw / (1.f + __expf(-raw));
                    else if (g.act == 2) {
                        const float a = g.aux[(long)z * g.bsX + (long)gm * g.ldx + gn];
                        const float s = 1.f / (1.f + __expf(-a));
                        av = raw * (s * (1.f + a * (1.f - s)));
                    }
                    float v = g.s1 * av;
                    if (g.resid) v += g.s2 * g.resid[(long)z * g.bsR + (long)gm * g.ldr + gn];
                    if (g.Cf) g.Cf[(long)z * g.bsC + (long)gm * g.ldc + gn] = (g.act == 1) ? raw : v;
                    if (g.Ch) g.Ch[(long)z * g.bsH + (long)gm * g.ldh + gn] = (_Float16)v;
                    acc[i][j][r] = v;
                }
            }
        }
    }

    // ---- coalesced transposed store via LDS ----
    if (g.Ct && (g.act != 4 || n0 < 1024)) {
        constexpr int TP = BM + 8;
        __syncthreads();
#pragma unroll
        for (int i = 0; i < FA; ++i) {
            const int lm = wr * WM + i * 16 + kq * 4;
#pragma unroll
            for (int j = 0; j < FB; ++j) {
                const int ln = wc * WN + j * 16 + fr;
#pragma unroll
                for (int r = 0; r < 4; ++r)
                    smem[ln * TP + lm + r] = (_Float16)acc[i][j][r];
            }
        }
        __syncthreads();
        constexpr int TPC = 256 / BN;       // threads per output column
        constexpr int SEG = BM / TPC;       // rows stored per thread
        const int ln = tid / TPC, part = tid % TPC;
        const int gn = n0 + ln;
        if (gn < g.N) {
            const int gmb = m0 + part * SEG;
            _Float16* dst = g.Ct + (long)z * g.bsT + (long)gn * g.ldt + gmb;
            const _Float16* src = &smem[ln * TP + part * SEG];
#pragma unroll
            for (int gi = 0; gi < SEG / 8; ++gi)
                if (gmb + gi * 8 < g.M)
                    *(uint4*)(dst + gi * 8) = *(const uint4*)(src + gi * 8);
        }
    }
}

// ---- fused momentum + weight update + f16 cast + transpose ----
// blocks 0..511: w1 (R=2048,C=1024) -> mom1,w1m RMW, w1row f16, w1T f16 [1024][2048]
// blocks 512..1023: w0 (R=1024,C=2048) -> mom0,w0m RMW, w0T f16 [2048][1024]
__global__ void momupT_k(const float* __restrict__ dW1, float* __restrict__ mom1,
                         float* __restrict__ w1m, _Float16* __restrict__ w1row,
                         _Float16* __restrict__ w1t,
                         const float* __restrict__ dW0, float* __restrict__ mom0,
                         float* __restrict__ w0m, _Float16* __restrict__ w0t)
{
    __shared__ _Float16 t[64][65];
    const int b = blockIdx.x;
    const int tid = threadIdx.x;
    const float* dW; float* mom; float* wm; _Float16* wrow; _Float16* wT;
    int C, RT, r0, c0;
    if (b < 512) {
        dW = dW1; mom = mom1; wm = w1m; wrow = w1row; wT = w1t;
        C = 1024; RT = 2048;
        r0 = (b >> 4) << 6; c0 = (b & 15) << 6;
    } else {
        const int bb = b - 512;
        dW = dW0; mom = mom0; wm = w0m; wrow = nullptr; wT = w0t;
        C = 2048; RT = 1024;
        r0 = (bb >> 5) << 6; c0 = (bb & 31) << 6;
    }
#pragma unroll
    for (int i = 0; i < 4; ++i) {
        const int f = i * 256 + tid;
        const int rr = f >> 4;              // 0..63
        const int c4 = (f & 15) << 2;       // 0..60
        const long idx = (long)(r0 + rr) * C + c0 + c4;
        const float4 d = *(const float4*)(dW + idx);
        float4 mo = *(const float4*)(mom + idx);
        float4 w  = *(const float4*)(wm + idx);
        mo.x = 0.9f * mo.x + d.x; mo.y = 0.9f * mo.y + d.y;
        mo.z = 0.9f * mo.z + d.z; mo.w = 0.9f * mo.w + d.w;
        w.x = 0.99f * w.x - 0.01f * mo.x; w.y = 0.99f * w.y - 0.01f * mo.y;
        w.z = 0.99f * w.z - 0.01f * mo.z; w.w = 0.99f * w.w - 0.01f * mo.w;
        *(float4*)(mom + idx) = mo;
        *(float4*)(wm + idx) = w;
        const _Float16 h0 = (_Float16)w.x, h1 = (_Float16)w.y,
                       h2 = (_Float16)w.z, h3 = (_Float16)w.w;
        if (wrow) {
            wrow[idx] = h0; wrow[idx + 1] = h1;
            wrow[idx + 2] = h2; wrow[idx + 3] = h3;
        }
        t[rr][c4] = h0; t[rr][c4 + 1] = h1; t[rr][c4 + 2] = h2; t[rr][c4 + 3] = h3;
    }
    __syncthreads();
#pragma unroll
    for (int i = 0; i < 4; ++i) {
        const int f = i * 256 + tid;
        const int cc = f >> 4;              // tile col (output row)
        const int rr4 = (f & 15) << 2;      // tile rows, 4 consecutive
        ushort4 u;
        u.x = *(const unsigned short*)&t[rr4][cc];
        u.y = *(const unsigned short*)&t[rr4 + 1][cc];
        u.z = *(const unsigned short*)&t[rr4 + 2][cc];
        u.w = *(const unsigned short*)&t[rr4 + 3][cc];
        *(ushort4*)(wT + (long)(c0 + cc) * RT + r0 + rr4) = u;
    }
}

// ---- elementwise / rowwise ----
__global__ void cvt_k(const float* __restrict__ in, _Float16* __restrict__ out, long n)
{
    long i = ((long)blockIdx.x * 256 + threadIdx.x) * 4;
    if (i >= n) return;
    const float4 v = *(const float4*)(in + i);
    out[i] = (_Float16)v.x; out[i + 1] = (_Float16)v.y;
    out[i + 2] = (_Float16)v.z; out[i + 3] = (_Float16)v.w;
}

__global__ void cvtT_k(const float* __restrict__ in, _Float16* __restrict__ out, int R, int C)
{
    __shared__ _Float16 t[64][65];
    const int c0 = blockIdx.x * 64, r0 = blockIdx.y * 64;
    const int tid = threadIdx.x;
    for (int i = 0; i < 16; ++i) {
        const int lin = i * 256 + tid;
        const int r = lin >> 6, cc = lin & 63;
        t[r][cc] = (_Float16)in[(long)(r0 + r) * C + c0 + cc];
    }
    __syncthreads();
    for (int i = 0; i < 16; ++i) {
        const int lin = i * 256 + tid;
        const int r2 = lin >> 6, c2 = lin & 63;
        out[(long)(c0 + r2) * R + r0 + c2] = t[c2][r2];
    }
}

__global__ void l2n16s_k(const float* __restrict__ in, long ld,
                         _Float16* __restrict__ out, float scale)
{
    const long row = blockIdx.x;
    const float* p = in + row * ld;
    _Float16* q = out + row * DD;
    const int t = threadIdx.x;
    float e0 = p[t], e1 = p[t + 256], e2 = p[t + 512], e3 = p[t + 768];
    __shared__ float rq[256];
    rq[t] = e0 * e0 + e1 * e1 + e2 * e2 + e3 * e3;
    __syncthreads();
    for (int k = 128; k; k >>= 1) { if (t < k) rq[t] += rq[t + k]; __syncthreads(); }
    const float f = scale / fmaxf(sqrtf(rq[0]), 1e-12f);
    q[t] = (_Float16)(e0 * f); q[t + 256] = (_Float16)(e1 * f);
    q[t + 512] = (_Float16)(e2 * f); q[t + 768] = (_Float16)(e3 * f);
}

// fused q + k l2norm from F32QK [2080][2048]
__global__ void l2qk_k(const float* __restrict__ qk, _Float16* __restrict__ q16,
                       _Float16* __restrict__ k16)
{
    const int blk = blockIdx.x;     // 0..3103
    const float* p; _Float16* o; float scale;
    if (blk < 1024) {
        const int b = blk >> 9, r = blk & 511;
        p = qk + (long)(b * SB + PPc + CC + r) * 2048;
        o = q16 + (long)blk * DD; scale = 32.f;
    } else {
        const int row = blk - 1024;
        p = qk + (long)row * 2048 + 1024;
        o = k16 + (long)row * DD; scale = 1.f;
    }
    const int t = threadIdx.x;
    float e0 = p[t], e1 = p[t + 256], e2 = p[t + 512], e3 = p[t + 768];
    __shared__ float rq[256];
    rq[t] = e0 * e0 + e1 * e1 + e2 * e2 + e3 * e3;
    __syncthreads();
    for (int k = 128; k; k >>= 1) { if (t < k) rq[t] += rq[t + k]; __syncthreads(); }
    const float f = scale / fmaxf(sqrtf(rq[0]), 1e-12f);
    o[t] = (_Float16)(e0 * f); o[t + 256] = (_Float16)(e1 * f);
    o[t + 512] = (_Float16)(e2 * f); o[t + 768] = (_Float16)(e3 * f);
}

// h rows come as two split-K halves (h + h2) plus bias hb, summed here
__global__ void lnaug_k(const float* __restrict__ x, const float* __restrict__ pers,
                        const float* __restrict__ h, const float* __restrict__ h2,
                        const float* __restrict__ hb,
                        const float* __restrict__ g, const float* __restrict__ b,
                        _Float16* __restrict__ out, int c)
{
    const int row = blockIdx.x;             // 0..2079
    const int bb = row / SB, i = row % SB;
    const float* p;
    const float* p2 = nullptr;
    if (i < PPc) p = pers + (long)i * DD;
    else if (i < PPc + CC) {
        const long off = (long)(bb * CC + i - PPc) * DD;
        p = h + off; p2 = h2 + off;
    }
    else p = x + (long)(bb * TT + c * CC + (i - PPc - CC)) * DD;
    _Float16* q = out + (long)row * DD;
    const int t = threadIdx.x;
    float e0 = p[t], e1 = p[t + 256], e2 = p[t + 512], e3 = p[t + 768];
    if (p2) {
        e0 += p2[t]       + hb[t];
        e1 += p2[t + 256] + hb[t + 256];
        e2 += p2[t + 512] + hb[t + 512];
        e3 += p2[t + 768] + hb[t + 768];
    }
    __shared__ float rs[256], rq[256];
    rs[t] = e0 + e1 + e2 + e3;
    rq[t] = e0 * e0 + e1 * e1 + e2 * e2 + e3 * e3;
    __syncthreads();
    for (int k = 128; k; k >>= 1) {
        if (t < k) { rs[t] += rs[t + k]; rq[t] += rq[t + k]; }
        __syncthreads();
    }
    const float mean = rs[0] * (1.f / DD);
    const float inv = rsqrtf(rq[0] * (1.f / DD) - mean * mean + 1e-5f);
    q[t]       = (_Float16)((e0 - mean) * inv * g[t]       + b[t]);
    q[t + 256] = (_Float16)((e1 - mean) * inv * g[t + 256] + b[t + 256]);
    q[t + 512] = (_Float16)((e2 - mean) * inv * g[t + 512] + b[t + 512]);
    q[t + 768] = (_Float16)((e3 - mean) * inv * g[t + 768] + b[t + 768]);
}

__global__ void softmax16_k(const float* __restrict__ sc, _Float16* __restrict__ pr)
{
    const int blk = blockIdx.x;             // 0..1023
    const int r = blk & 511;
    const int i = PPc + CC + r;
    const float* p = sc + (long)blk * SB;
    _Float16* q = pr + (long)blk * KA;
    const int t = threadIdx.x;
    __shared__ float red[256];
    float mx = -3.0e38f;
    for (int j = t; j < SB; j += 256)
        if (j <= i) mx = fmaxf(mx, p[j]);
    red[t] = mx; __syncthreads();
    for (int k = 128; k; k >>= 1) { if (t < k) red[t] = fmaxf(red[t], red[t + k]); __syncthreads(); }
    mx = red[0]; __syncthreads();
    float sum = 0.f;
    for (int j = t; j < SB; j += 256)
        if (j <= i) sum += __expf(p[j] - mx);
    red[t] = sum; __syncthreads();
    for (int k = 128; k; k >>= 1) { if (t < k) red[t] += red[t + k]; __syncthreads(); }
    const float inv = 1.f / red[0];
    for (int j = t; j < KA; j += 256) {
        float e = 0.f;
        if (j < SB && j <= i) e = __expf(p[j] - mx) * inv;
        q[j] = (_Float16)e;
    }
}

// gp and mo each arrive as two split-K halves; mo gets bias mb added here
__global__ void gateln2_k(const float* __restrict__ yt,
                          const float* __restrict__ gp, const float* __restrict__ gp2,
                          const float* __restrict__ mo, const float* __restrict__ mo2,
                          const float* __restrict__ mb,
                          const float* __restrict__ g, const float* __restrict__ b,
                          float* __restrict__ OF, _Float16* __restrict__ o16)
{
    const long row = blockIdx.x;
    const int t = threadIdx.x;
    float e[4];
    __shared__ float rs[256], rq[256];
    float ssum = 0.f, qsum = 0.f;
#pragma unroll
    for (int k = 0; k < 4; ++k) {
        const int cc = t + k * 256;
        const long idx = row * DD + cc;
        const float gv = gp[idx] + gp2[idx];
        const float mv = mo[idx] + mo2[idx] + mb[cc];
        const float s = 1.f / (1.f + __expf(-gv));
        e[k] = yt[idx] * s + mv * (1.f - s);
        OF[idx] = e[k];
        ssum += e[k]; qsum += e[k] * e[k];
    }
    rs[t] = ssum; rq[t] = qsum;
    __syncthreads();
    for (int k = 128; k; k >>= 1) {
        if (t < k) { rs[t] += rs[t + k]; rq[t] += rq[t + k]; }
        __syncthreads();
    }
    const float mean = rs[0] * (1.f / DD);
    const float inv = rsqrtf(rq[0] * (1.f / DD) - mean * mean + 1e-5f);
#pragma unroll
    for (int k = 0; k < 4; ++k) {
        const int cc = t + k * 256;
        o16[row * DD + cc] = (_Float16)((e[k] - mean) * inv * g[cc] + b[cc]);
    }
}

// fused tail: blocks 0..3071 rowsum + bias momentum update (rT16->mb1, da0T->mb0);
// 3072..4095 l2norm(F32A row)->qm16; 4096..5119 LN(YTF row)->gl16
__global__ void tailfuse_k(const _Float16* __restrict__ rT, const _Float16* __restrict__ daT,
                           float* __restrict__ mb0, float* __restrict__ mob0,
                           float* __restrict__ mb1, float* __restrict__ mob1,
                           const float* __restrict__ qmp, _Float16* __restrict__ qm16,
                           const float* __restrict__ ytf, const float* __restrict__ gg,
                           const float* __restrict__ gb, _Float16* __restrict__ gl)
{
    const int blk = blockIdx.x;
    const int t = threadIdx.x;
    __shared__ float rs[256], rq[256];
    if (blk < 3072) {
        const _Float16* p = (blk < 1024) ? rT + (long)blk * 1024
                                         : daT + (long)(blk - 1024) * 1024;
        rs[t] = (float)p[t] + (float)p[t + 256] + (float)p[t + 512] + (float)p[t + 768];
        __syncthreads();
        for (int k = 128; k; k >>= 1) { if (t < k) rs[t] += rs[t + k]; __syncthreads(); }
        if (t == 0) {
            const float d = rs[0];
            if (blk < 1024) {
                const float m = 0.9f * mob1[blk] + d;
                mob1[blk] = m;
                mb1[blk] = 0.99f * mb1[blk] - 0.01f * m;
            } else {
                const int j = blk - 1024;
                const float m = 0.9f * mob0[j] + d;
                mob0[j] = m;
                mb0[j] = 0.99f * mb0[j] - 0.01f * m;
            }
        }
    } else if (blk < 4096) {
        const long row = blk - 3072;
        const float* p = qmp + row * DD;
        _Float16* q = qm16 + row * DD;
        float e0 = p[t], e1 = p[t + 256], e2 = p[t + 512], e3 = p[t + 768];
        rq[t] = e0 * e0 + e1 * e1 + e2 * e2 + e3 * e3;
        __syncthreads();
        for (int k = 128; k; k >>= 1) { if (t < k) rq[t] += rq[t + k]; __syncthreads(); }
        const float f = 1.f / fmaxf(sqrtf(rq[0]), 1e-12f);
        q[t] = (_Float16)(e0 * f); q[t + 256] = (_Float16)(e1 * f);
        q[t + 512] = (_Float16)(e2 * f); q[t + 768] = (_Float16)(e3 * f);
    } else {
        const long row = blk - 4096;
        const float* p = ytf + row * DD;
        _Float16* q = gl + row * DD;
        float e0 = p[t], e1 = p[t + 256], e2 = p[t + 512], e3 = p[t + 768];
        rs[t] = e0 + e1 + e2 + e3;
        rq[t] = e0 * e0 + e1 * e1 + e2 * e2 + e3 * e3;
        __syncthreads();
        for (int k = 128; k; k >>= 1) {
            if (t < k) { rs[t] += rs[t + k]; rq[t] += rq[t + k]; }
            __syncthreads();
        }
        const float mean = rs[0] * (1.f / DD);
        const float inv = rsqrtf(rq[0] * (1.f / DD) - mean * mean + 1e-5f);
        q[t]       = (_Float16)((e0 - mean) * inv * gg[t]       + gb[t]);
        q[t + 256] = (_Float16)((e1 - mean) * inv * gg[t + 256] + gb[t + 256]);
        q[t + 512] = (_Float16)((e2 - mean) * inv * gg[t + 512] + gb[t + 512]);
        q[t + 768] = (_Float16)((e3 - mean) * inv * gg[t + 768] + gb[t + 768]);
    }
}

__global__ void zero_k(float* __restrict__ p, long n)
{
    long i = (long)blockIdx.x * 256 + threadIdx.x;
    const long st = (long)gridDim.x * 256;
    for (; i < n; i += st) p[i] = 0.f;
}

extern "C" void kernel_launch(void* const* d_in, const int* in_sizes, int n_in,
                              void* d_out, int out_size, void* d_ws, size_t ws_size,
                              hipStream_t stream)
{
    const float* x          = (const float*)d_in[0];
    const float* wq_ctx     = (const float*)d_in[1];
    const float* wq         = (const float*)d_in[2];
    const float* wk         = (const float*)d_in[3];
    const float* wv         = (const float*)d_in[4];
    const float* w_attn_out = (const float*)d_in[5];
    const float* w_gate     = (const float*)d_in[6];
    const float* gate_g     = (const float*)d_in[7];
    const float* gate_b     = (const float*)d_in[8];
    const float* n1_g       = (const float*)d_in[9];
    const float* n1_b       = (const float*)d_in[10];
    const float* n2_g       = (const float*)d_in[11];
    const float* n2_b       = (const float*)d_in[12];
    const float* ffn_w1     = (const float*)d_in[13];
    const float* ffn_b1     = (const float*)d_in[14];
    const float* ffn_w2     = (const float*)d_in[15];
    const float* ffn_b2     = (const float*)d_in[16];
    const float* pers       = (const float*)d_in[17];
    const float* mem_w0_in  = (const float*)d_in[18];
    const float* mem_b0_in  = (const float*)d_in[19];
    const float* mem_w1_in  = (const float*)d_in[20];
    const float* mem_b1_in  = (const float*)d_in[21];
    const float* mem_wk     = (const float*)d_in[22];
    const float* mem_wv     = (const float*)d_in[23];
    float* out = (float*)d_out;
    (void)in_sizes; (void)n_in; (void)out_size; (void)ws_size;

    char* cur = (char*)d_ws;
    auto allocF = [&](size_t n) { float* p = (float*)cur; cur += n * 4; return p; };
    auto allocH = [&](size_t n) { _Float16* p = (_Float16*)cur; cur += n * 2; return p; };

    float* mw0   = allocF((size_t)DD * HH);
    float* mw1   = allocF((size_t)HH * DD);
    float* mb0   = allocF(HH);
    float* mb1   = allocF(DD);
    float* mom   = allocF((size_t)DD * HH * 2 + HH + DD);
    float* mom_w0 = mom, *mom_w1 = mom + (size_t)DD * HH;
    float* mom_b0 = mom_w1 + (size_t)HH * DD, *mom_b1 = mom_b0 + HH;
    float* F32A  = allocF((size_t)1024 * DD);
    float* F32B  = allocF((size_t)1024 * DD);
    float* F32C  = allocF((size_t)1024 * HH);
    float* F32QK = allocF((size_t)2112 * 2048);
    float* YTF   = allocF((size_t)1024 * DD);
    float* OF    = allocF((size_t)1024 * DD);

    _Float16* x16    = allocH((size_t)2 * TT * DD);
    _Float16* wqcT   = allocH((size_t)DD * DD);
    _Float16* wqkT   = allocH((size_t)2048 * DD);
    _Float16* wvT    = allocH((size_t)DD * DD);
    _Float16* waoT   = allocH((size_t)DD * DD);
    _Float16* wgT    = allocH((size_t)DD * DD);
    _Float16* wmixT  = allocH((size_t)3072 * DD);
    _Float16* f1T    = allocH((size_t)FFd * DD);
    _Float16* f2T    = allocH((size_t)DD * FFd);
    _Float16* w0T    = allocH((size_t)HH * DD);
    _Float16* w1T    = allocH((size_t)DD * HH);
    _Float16* w1p    = allocH((size_t)HH * DD);
    _Float16* xn16   = allocH((size_t)1024 * DD);
    _Float16* h116   = allocH((size_t)1024 * HH);
    _Float16* laug16 = allocH((size_t)2208 * DD);
    _Float16* q16    = allocH((size_t)1024 * DD);
    _Float16* k16    = allocH((size_t)2208 * DD);
    _Float16* vT16   = allocH((size_t)2 * DD * KA);
    _Float16* pr16   = allocH((size_t)2 * 512 * KA);
    _Float16* ao16   = allocH((size_t)1024 * DD);
    _Float16* yt16   = allocH((size_t)1024 * DD);
    _Float16* kk16   = allocH((size_t)1024 * DD);
    _Float16* kkT16  = allocH((size_t)DD * 1024);
    _Float16* hs16   = allocH((size_t)1024 * HH);
    _Float16* hsT16  = allocH((size_t)HH * 1024);
    _Float16* r16    = allocH((size_t)1024 * DD);
    _Float16* rT16   = allocH((size_t)DD * 1024);
    _Float16* da0T   = allocH((size_t)HH * 1024);
    _Float16* qm16   = allocH((size_t)1024 * DD);
    _Float16* a216   = allocH((size_t)1024 * HH);
    _Float16* gl16   = allocH((size_t)1024 * DD);
    _Float16* h216   = allocH((size_t)1024 * DD);
    _Float16* f116   = allocH((size_t)1024 * FFd);

    // split-K z=1 scratch (inside F32QK, free at the relevant points)
    float* SPL0 = F32QK;                               // 4 MB
    float* SPL1 = F32QK + (size_t)1024 * 1024;         // 4 MB

    auto launch = [&](int nz, GP g) {
        if (!g.ldA) g.ldA = g.K;
        if (!g.ldB) g.ldB = g.K;
        dim3 grid((g.N + 63) / 64, (g.M + 63) / 64, nz);
        gemm16<64, 64><<<grid, 256, 0, stream>>>(g);
    };

    // ---- init ----
    hipMemcpyAsync(mw0, mem_w0_in, sizeof(float) * DD * HH, hipMemcpyDeviceToDevice, stream);
    hipMemcpyAsync(mw1, mem_w1_in, sizeof(float) * HH * DD, hipMemcpyDeviceToDevice, stream);
    hipMemcpyAsync(mb0, mem_b0_in, sizeof(float) * HH, hipMemcpyDeviceToDevice, stream);
    hipMemcpyAsync(mb1, mem_b1_in, sizeof(float) * DD, hipMemcpyDeviceToDevice, stream);
    zero_k<<<4096, 256, 0, stream>>>(mom, (long)DD * HH * 2 + HH + DD);
    cvt_k<<<(2 * TT * DD) / 1024, 256, 0, stream>>>(x, x16, (long)2 * TT * DD);
    auto T64 = [&](const float* in, _Float16* o, int R, int C) {
        cvtT_k<<<dim3(C / 64, R / 64), 256, 0, stream>>>(in, o, R, C);
    };
    T64(wq_ctx, wqcT, DD, DD);
    T64(wq, wqkT, DD, DD); T64(wk, wqkT + (size_t)1024 * DD, DD, DD);
    T64(wv, wvT, DD, DD); T64(w_attn_out, waoT, DD, DD); T64(w_gate, wgT, DD, DD);
    T64(mem_wk, wmixT, DD, DD); T64(mem_wv, wmixT + (size_t)1024 * DD, DD, DD);
    T64(wq_ctx, wmixT + (size_t)2048 * DD, DD, DD);
    T64(ffn_w1, f1T, DD, FFd); T64(ffn_w2, f2T, FFd, DD);
    T64(mem_w0_in, w0T, DD, HH); T64(mem_w1_in, w1T, HH, DD);
    cvt_k<<<(HH * DD) / 1024, 256, 0, stream>>>(mem_w1_in, w1p, (long)HH * DD);

    for (int c = 0; c < NCH; ++c) {
        GP g;
        // 1. xn_pre = seg @ wq_ctx  (z=2)
        g = GP{}; g.A = x16 + (long)c * CC * DD; g.bsA = (long)TT * DD; g.Bt = wqcT;
        g.Cf = F32A; g.ldc = DD; g.bsC = (long)CC * DD;
        g.s1 = 1.f; g.M = CC; g.N = DD; g.K = DD;
        launch(2, g);
        l2n16s_k<<<1024, 256, 0, stream>>>(F32A, DD, xn16, 1.f);
        // 2. h = mem_mlp(mem, xn)
        g = GP{}; g.A = xn16; g.Bt = w0T; g.bias = mb0; g.Ch = h116; g.ldh = HH;
        g.s1 = 1.f; g.M = 1024; g.N = HH; g.K = DD; g.act = 1;
        launch(1, g);
        // 2b split-K x2 (NO bias here; mb1 added in lnaug): halves -> F32B, SPL0
        g = GP{}; g.A = h116; g.bsA = 1024; g.ldA = HH;
        g.Bt = w1T; g.bsB = 1024; g.ldB = HH;
        g.Cf = F32B; g.ldc = DD; g.bsC = (long)(SPL0 - F32B);
        g.s1 = 1.f; g.M = 1024; g.N = DD; g.K = 1024;
        launch(2, g);
        lnaug_k<<<2 * SB, 256, 0, stream>>>(x, pers, F32B, SPL0, mb1, n1_g, n1_b, laug16, c);
        // 3. q|k fused
        g = GP{}; g.A = laug16; g.Bt = wqkT; g.Cf = F32QK; g.ldc = 2048;
        g.s1 = 1.f; g.M = 2 * SB; g.N = 2048; g.K = DD;
        launch(1, g);
        l2qk_k<<<3104, 256, 0, stream>>>(F32QK, q16, k16);
        // 4. v (transposed out)
        g = GP{}; g.A = laug16; g.bsA = (long)SB * DD; g.Bt = wvT;
        g.Ct = vT16; g.ldt = KA; g.bsT = (long)DD * KA;
        g.s1 = 1.f; g.M = SB; g.N = DD; g.K = DD;
        launch(2, g);
        // 5. scores + softmax + PV
        g = GP{}; g.A = q16; g.bsA = (long)512 * DD; g.Bt = k16; g.bsB = (long)SB * DD;
        g.Cf = F32C; g.ldc = SB; g.bsC = (long)512 * SB;
        g.s1 = 1.f; g.M = 512; g.N = SB; g.K = DD;
        launch(2, g);
        softmax16_k<<<1024, 256, 0, stream>>>(F32C, pr16);
        g = GP{}; g.A = pr16; g.bsA = (long)512 * KA; g.Bt = vT16; g.bsB = (long)DD * KA;
        g.Ch = ao16; g.ldh = DD; g.bsH = (long)512 * DD;
        g.s1 = 1.f; g.M = 512; g.N = DD; g.K = KA;
        launch(2, g);
        // 6. y_t = seg + attn @ wao
        g = GP{}; g.A = ao16; g.bsA = (long)512 * DD; g.Bt = waoT;
        g.resid = x + (long)c * CC * DD; g.ldr = DD; g.bsR = (long)TT * DD;
        g.Cf = YTF; g.ldc = DD; g.bsC = (long)512 * DD;
        g.Ch = yt16; g.ldh = DD; g.bsH = (long)512 * DD;
        g.s1 = 1.f; g.s2 = 1.f; g.M = 512; g.N = DD; g.K = DD;
        launch(2, g);
        // 7. kk | vv | qm_pre fused (act 4) with kkT via LDS transpose
        g = GP{}; g.A = yt16; g.Bt = wmixT; g.Ch = kk16; g.Ct = kkT16; g.ldt = 1024;
        g.Cf = F32B; g.Cf2 = F32A;
        g.s1 = 1.f; g.M = 1024; g.N = 3072; g.K = DD; g.act = 4;
        launch(1, g);
        // 8. a0 = kk@w0+b0 (raw) ; hs/hsT = silu
        g = GP{}; g.A = kk16; g.Bt = w0T; g.bias = mb0; g.Cf = F32C; g.ldc = HH;
        g.Ch = hs16; g.ldh = HH; g.Ct = hsT16; g.ldt = 1024;
        g.s1 = 1.f; g.M = 1024; g.N = HH; g.K = DD; g.act = 1;
        launch(1, g);
        // 9. r = (hs@w1 + b1 - vv)/1024
        g = GP{}; g.A = hs16; g.Bt = w1T; g.bias = mb1;
        g.resid = F32B; g.ldr = DD;
        g.Ch = r16; g.ldh = DD; g.Ct = rT16; g.ldt = 1024;
        g.s1 = 1.f / 1024.f; g.s2 = -1.f / 1024.f; g.M = 1024; g.N = DD; g.K = HH;
        launch(1, g);
        // 10. da0T = (r @ w1_old^T) * dsilu(a0)   (before w1 update!)
        g = GP{}; g.A = r16; g.Bt = w1p; g.aux = F32C; g.ldx = HH;
        g.Ct = da0T; g.ldt = 1024;
        g.s1 = 1.f; g.M = 1024; g.N = HH; g.K = DD; g.act = 2;
        launch(1, g);
        // fused tail: rowsums + bias momentum update | l2norm(qm_pre) | LN(YTF)
        tailfuse_k<<<5120, 256, 0, stream>>>(rT16, da0T, mb0, mom_b0, mb1, mom_b1,
                                             F32A, qm16, YTF, gate_g, gate_b, gl16);
        // 11a. dW1 = hsT @ rT (plain GEMM, f32 -> F32C; F32C free after step 10)
        g = GP{}; g.A = hsT16; g.Bt = rT16; g.Cf = F32C; g.ldc = DD;
        g.s1 = 1.f; g.M = HH; g.N = DD; g.K = 1024;
        launch(1, g);
        // 11b. dW0 = kkT @ da0T (plain GEMM, f32 -> F32QK; free after l2qk)
        g = GP{}; g.A = kkT16; g.Bt = da0T; g.Cf = F32QK; g.ldc = HH;
        g.s1 = 1.f; g.M = DD; g.N = HH; g.K = 1024;
        launch(1, g);
        // 11c. fused momentum + weight update + f16 cast + transpose (both weights)
        momupT_k<<<1024, 256, 0, stream>>>(F32C, mom_w1, mw1, w1p, w1T,
                                           F32QK, mom_w0, mw0, w0T);
        // 13. mem_out = mem_mlp(new mem, qm16)
        g = GP{}; g.A = qm16; g.Bt = w0T; g.bias = mb0; g.Ch = a216; g.ldh = HH;
        g.s1 = 1.f; g.M = 1024; g.N = HH; g.K = DD; g.act = 1;
        launch(1, g);
        // 13b split-K x2 (NO bias; mb1 added in gateln2): halves -> F32B, SPL0
        g = GP{}; g.A = a216; g.bsA = 1024; g.ldA = HH;
        g.Bt = w1T; g.bsB = 1024; g.ldB = HH;
        g.Cf = F32B; g.ldc = DD; g.bsC = (long)(SPL0 - F32B);
        g.s1 = 1.f; g.M = 1024; g.N = DD; g.K = 1024;
        launch(2, g);
        // 14 split-K x2: gate proj halves -> F32C (z0) and SPL1 (z1); no bias in ref
        g = GP{}; g.A = gl16; g.bsA = 512; g.ldA = DD;
        g.Bt = wgT; g.bsB = 512; g.ldB = DD;
        g.Cf = F32C; g.ldc = DD; g.bsC = (long)(SPL1 - F32C);
        g.s1 = 1.f; g.M = 1024; g.N = DD; g.K = 512;
        launch(2, g);
        gateln2_k<<<1024, 256, 0, stream>>>(YTF, F32C, SPL1, F32B, SPL0, mb1,
                                            n2_g, n2_b, OF, h216);
        // 15. FFN
        g = GP{}; g.A = h216; g.Bt = f1T; g.bias = ffn_b1; g.Ch = f116; g.ldh = FFd;
        g.s1 = 1.f; g.M = 1024; g.N = FFd; g.K = DD; g.act = 1;
        launch(1, g);
        g = GP{}; g.A = f116; g.bsA = (long)512 * FFd; g.Bt = f2T; g.bias = ffn_b2;
        g.resid = OF; g.ldr = DD; g.bsR = (long)512 * DD;
        g.Cf = out + (long)c * CC * DD; g.ldc = DD; g.bsC = (long)TT * DD;
        g.s1 = 1.f; g.s2 = 1.f; g.M = 512; g.N = DD; g.K = FFd;
        launch(2, g);
    }
}

// Round 11
// 2879.944 us; speedup vs baseline: 1.1363x; 1.0551x over previous
//
#include <hip/hip_runtime.h>

#define DD 1024
#define HH 2048
#define TT 4096
#define CC 512
#define PPc 16
#define SB 1040   // per-batch aug rows
#define KA 1088   // padded attention K (multiple of 64)
#define FFd 4096
#define NCH 8

typedef _Float16 f16x8 __attribute__((ext_vector_type(8)));
typedef float f32x4 __attribute__((ext_vector_type(4)));

typedef const __attribute__((address_space(1))) _Float16* gas_t;
typedef __attribute__((address_space(3))) _Float16* las_t;

__device__ __forceinline__ void async_cp16(const _Float16* g, _Float16* l) {
    __builtin_amdgcn_global_load_lds((gas_t)g, (las_t)l, 16, 0, 0);
}

template<int N> __device__ __forceinline__ void waitvm() {
    static_assert(N == 0 || N == 2 || N == 3 || N == 4 || N == 6 || N == 8, "unsupported vmcnt");
    if constexpr (N == 0)      asm volatile("s_waitcnt vmcnt(0)" ::: "memory");
    else if constexpr (N == 2) asm volatile("s_waitcnt vmcnt(2)" ::: "memory");
    else if constexpr (N == 3) asm volatile("s_waitcnt vmcnt(3)" ::: "memory");
    else if constexpr (N == 4) asm volatile("s_waitcnt vmcnt(4)" ::: "memory");
    else if constexpr (N == 6) asm volatile("s_waitcnt vmcnt(6)" ::: "memory");
    else                       asm volatile("s_waitcnt vmcnt(8)" ::: "memory");
}
#define BARRIER() asm volatile("s_barrier" ::: "memory")

struct GP {
    const _Float16* A; long bsA, ldA;
    const _Float16* Bt; long bsB, ldB;
    const float* bias;
    const float* resid; long ldr, bsR;
    const float* aux;   long ldx, bsX;
    float* Cf; long ldc, bsC;
    _Float16* Ch; long ldh, bsH;
    _Float16* Ct; long ldt, bsT;
    float* Mom;
    float* Cf2;
    float s1, s2;
    int M, N, K, act;
};

// acts: 0 plain, 1 silu (Cf<-raw, Ch/Ct<-silu*s1+resid), 2 mul-by-dsilu(aux),
//       4 routing (n<1024 -> Ch(+Ct), <2048 -> Cf, else Cf2; all ld 1024)
// K % 64 == 0, K >= 128. Ct GEMMs require M % 8 == 0.
// ldA/ldB are A/B row strides (= K normally; > K for split-K via z where
// z*bsA is a COLUMN offset into each row). NOTE: split-K GEMMs must NOT set
// bias (each half would add it) — bias is applied in the consumer kernel.
// Pipeline: 3 LDS buffers of 64-k panels, prefetch distance 2, counted vmcnt,
// raw s_barrier. LDS slots XOR-swizzled (T2): global source pre-swizzled so
// global_load_lds stays linear; ds_read applies the same involution.
template<int BM, int BN>
__global__ __launch_bounds__(256) void gemm16(GP g)
{
    constexpr int WM = BM / 2, WN = BN / 2;
    constexpr int FA = WM / 16, FB = WN / 16;
    constexpr int LA = BM / 32, LB = BN / 32;   // 16B loads / thread / 64-k panel
    constexpr int LL = LA + LB;
    constexpr int APAN = BM * 64, BPAN = BN * 64;   // f16 per 64-k panel
    constexpr int NB = 3;
    __shared__ _Float16 smem[NB * (APAN + BPAN)];
    const int tid = threadIdx.x;

    // ---- XCD-aware bijective block swizzle (m204) ----
    const int gx = gridDim.x, gy = gridDim.y;
    const int nwg = gx * gy * (int)gridDim.z;
    const int orig = ((int)blockIdx.z * gy + (int)blockIdx.y) * gx + (int)blockIdx.x;
    const int xcd = orig & 7, loc = orig >> 3;
    const int q8 = nwg >> 3, r8 = nwg & 7;
    const int lid = (xcd < r8 ? xcd * (q8 + 1) : r8 * (q8 + 1) + (xcd - r8) * q8) + loc;
    const int bxi = lid % gx;
    const int rem = lid / gx;
    const int byi = rem % gy;
    const int z = rem / gy;

    const int K = g.K;
    const long ldA = g.ldA, ldB = g.ldB;
    const int m0 = byi * BM, n0 = bxi * BN;
    const _Float16* Ab = g.A + (long)z * g.bsA + (long)m0 * ldA;
    const _Float16* Bb = g.Bt + (long)z * g.bsB + (long)n0 * ldB;
    const int wave = tid >> 6, lane = tid & 63;
    const int wr = wave >> 1, wc = wave & 1;
    const int fr = lane & 15, kq = lane >> 4;
    const int srow = tid >> 3;             // 0..31 (row within 32-row load chunk)
    const int sc8 = (((tid & 7) ^ (srow & 7)) << 3);  // pre-swizzled 16B slot -> f16 col
    f32x4 acc[FA][FB] = {};

    auto stage = [&](int q, int kk) {
#pragma unroll
        for (int r = 0; r < LA; ++r)
            async_cp16(Ab + (long)(r * 32 + srow) * ldA + kk + sc8,
                       &smem[q * APAN + r * 2048 + wave * 512]);
#pragma unroll
        for (int r = 0; r < LB; ++r)
            async_cp16(Bb + (long)(r * 32 + srow) * ldB + kk + sc8,
                       &smem[NB * APAN + q * BPAN + r * 2048 + wave * 512]);
    };

    // logical 16B slot for (h,kq) is h*4+kq; swizzled slot = (h*4+kq) ^ (row&7),
    // row&7 == fr&7 for all fragments (wr*WM, wc*WN, i*16 are multiples of 8)
    const int sl0 = ((kq ^ (fr & 7)) << 3);        // h=0 f16 col offset
    const int sl1 = (((4 + kq) ^ (fr & 7)) << 3);  // h=1 f16 col offset

    auto compute = [&](int q) {
        f16x8 af[2][FA], bf[2][FB];
        const int abase = q * APAN;
#pragma unroll
        for (int i = 0; i < FA; ++i) {
            const int ro = (wr * WM + i * 16 + fr) * 64;
            af[0][i] = *(const f16x8*)&smem[abase + ro + sl0];
            af[1][i] = *(const f16x8*)&smem[abase + ro + sl1];
        }
        const int bbase = NB * APAN + q * BPAN;
#pragma unroll
        for (int j = 0; j < FB; ++j) {
            const int ro = (wc * WN + j * 16 + fr) * 64;
            bf[0][j] = *(const f16x8*)&smem[bbase + ro + sl0];
            bf[1][j] = *(const f16x8*)&smem[bbase + ro + sl1];
        }
        __builtin_amdgcn_s_setprio(1);
#pragma unroll
        for (int h = 0; h < 2; ++h)
#pragma unroll
            for (int i = 0; i < FA; ++i)
#pragma unroll
                for (int j = 0; j < FB; ++j)
                    acc[i][j] = __builtin_amdgcn_mfma_f32_16x16x32_f16(af[h][i], bf[h][j], acc[i][j], 0, 0, 0);
        __builtin_amdgcn_s_setprio(0);
    };

    const int nk = K >> 6;                 // 64-k panels (>= 2)
    stage(0, 0); stage(1, 64);
    int qc = 0, qs = 2;
    for (int t = 0; t < nk; ++t) {
        if (t + 1 < nk) waitvm<LL>(); else waitvm<0>();
        BARRIER();                          // panel t ready; slot qs free
        if (t + 2 < nk) stage(qs, (t + 2) << 6);
        compute(qc);
        qc = (qc == NB - 1) ? 0 : qc + 1;
        qs = (qs == NB - 1) ? 0 : qs + 1;
    }

    // ---- finalize values in acc ----
#pragma unroll
    for (int i = 0; i < FA; ++i) {
        const int gm0 = m0 + wr * WM + i * 16 + kq * 4;
#pragma unroll
        for (int j = 0; j < FB; ++j) {
            const int gn = n0 + wc * WN + j * 16 + fr;
            if (gn >= g.N) continue;
            if (g.act == 4) {
                const int seg = gn >> 10, gl = gn & 1023;
#pragma unroll
                for (int r = 0; r < 4; ++r) {
                    const int gm = gm0 + r;
                    if (gm >= g.M) continue;
                    const float v = acc[i][j][r];
                    if (seg == 0) g.Ch[(long)gm * 1024 + gl] = (_Float16)v;
                    else if (seg == 1) g.Cf[(long)gm * 1024 + gl] = v;
                    else g.Cf2[(long)gm * 1024 + gl] = v;
                }
            } else {
                const float bv = g.bias ? g.bias[gn] : 0.f;
#pragma unroll
                for (int r = 0; r < 4; ++r) {
                    const int gm = gm0 + r;
                    if (gm >= g.M) continue;
                    const float raw = acc[i][j][r] + bv;
                    float av = raw;
                    if (g.act == 1) av = raw / (1.f + __expf(-raw));
                    else if (g.act == 2) {
                        const float a = g.aux[(long)z * g.bsX + (long)gm * g.ldx + gn];
                        const float s = 1.f / (1.f + __expf(-a));
                        av = raw * (s * (1.f + a * (1.f - s)));
                    }
                    float v = g.s1 * av;
                    if (g.resid) v += g.s2 * g.resid[(long)z * g.bsR + (long)gm * g.ldr + gn];
                    if (g.Cf) g.Cf[(long)z * g.bsC + (long)gm * g.ldc + gn] = (g.act == 1) ? raw : v;
                    if (g.Ch) g.Ch[(long)z * g.bsH + (long)gm * g.ldh + gn] = (_Float16)v;
                    acc[i][j][r] = v;
                }
            }
        }
    }

    // ---- coalesced transposed store via LDS ----
    if (g.Ct && (g.act != 4 || n0 < 1024)) {
        constexpr int TP = BM + 8;
        __syncthreads();
#pragma unroll
        for (int i = 0; i < FA; ++i) {
            const int lm = wr * WM + i * 16 + kq * 4;
#pragma unroll
            for (int j = 0; j < FB; ++j) {
                const int ln = wc * WN + j * 16 + fr;
#pragma unroll
                for (int r = 0; r < 4; ++r)
                    smem[ln * TP + lm + r] = (_Float16)acc[i][j][r];
            }
        }
        __syncthreads();
        constexpr int TPC = 256 / BN;       // threads per output column
        constexpr int SEG = BM / TPC;       // rows stored per thread
        const int ln = tid / TPC, part = tid % TPC;
        const int gn = n0 + ln;
        if (gn < g.N) {
            const int gmb = m0 + part * SEG;
            _Float16* dst = g.Ct + (long)z * g.bsT + (long)gn * g.ldt + gmb;
            const _Float16* src = &smem[ln * TP + part * SEG];
#pragma unroll
            for (int gi = 0; gi < SEG / 8; ++gi)
                if (gmb + gi * 8 < g.M)
                    *(uint4*)(dst + gi * 8) = *(const uint4*)(src + gi * 8);
        }
    }
}

// ---- fused momentum + weight update + f16 cast + transpose ----
// blocks 0..511: w1 (R=2048,C=1024) -> mom1,w1m RMW, w1row f16, w1T f16 [1024][2048]
// blocks 512..1023: w0 (R=1024,C=2048) -> mom0,w0m RMW, w0T f16 [2048][1024]
__global__ void momupT_k(const float* __restrict__ dW1, float* __restrict__ mom1,
                         float* __restrict__ w1m, _Float16* __restrict__ w1row,
                         _Float16* __restrict__ w1t,
                         const float* __restrict__ dW0, float* __restrict__ mom0,
                         float* __restrict__ w0m, _Float16* __restrict__ w0t)
{
    __shared__ _Float16 t[64][65];
    const int b = blockIdx.x;
    const int tid = threadIdx.x;
    const float* dW; float* mom; float* wm; _Float16* wrow; _Float16* wT;
    int C, RT, r0, c0;
    if (b < 512) {
        dW = dW1; mom = mom1; wm = w1m; wrow = w1row; wT = w1t;
        C = 1024; RT = 2048;
        r0 = (b >> 4) << 6; c0 = (b & 15) << 6;
    } else {
        const int bb = b - 512;
        dW = dW0; mom = mom0; wm = w0m; wrow = nullptr; wT = w0t;
        C = 2048; RT = 1024;
        r0 = (bb >> 5) << 6; c0 = (bb & 31) << 6;
    }
#pragma unroll
    for (int i = 0; i < 4; ++i) {
        const int f = i * 256 + tid;
        const int rr = f >> 4;              // 0..63
        const int c4 = (f & 15) << 2;       // 0..60
        const long idx = (long)(r0 + rr) * C + c0 + c4;
        const float4 d = *(const float4*)(dW + idx);
        float4 mo = *(const float4*)(mom + idx);
        float4 w  = *(const float4*)(wm + idx);
        mo.x = 0.9f * mo.x + d.x; mo.y = 0.9f * mo.y + d.y;
        mo.z = 0.9f * mo.z + d.z; mo.w = 0.9f * mo.w + d.w;
        w.x = 0.99f * w.x - 0.01f * mo.x; w.y = 0.99f * w.y - 0.01f * mo.y;
        w.z = 0.99f * w.z - 0.01f * mo.z; w.w = 0.99f * w.w - 0.01f * mo.w;
        *(float4*)(mom + idx) = mo;
        *(float4*)(wm + idx) = w;
        const _Float16 h0 = (_Float16)w.x, h1 = (_Float16)w.y,
                       h2 = (_Float16)w.z, h3 = (_Float16)w.w;
        if (wrow) {
            wrow[idx] = h0; wrow[idx + 1] = h1;
            wrow[idx + 2] = h2; wrow[idx + 3] = h3;
        }
        t[rr][c4] = h0; t[rr][c4 + 1] = h1; t[rr][c4 + 2] = h2; t[rr][c4 + 3] = h3;
    }
    __syncthreads();
#pragma unroll
    for (int i = 0; i < 4; ++i) {
        const int f = i * 256 + tid;
        const int cc = f >> 4;              // tile col (output row)
        const int rr4 = (f & 15) << 2;      // tile rows, 4 consecutive
        ushort4 u;
        u.x = *(const unsigned short*)&t[rr4][cc];
        u.y = *(const unsigned short*)&t[rr4 + 1][cc];
        u.z = *(const unsigned short*)&t[rr4 + 2][cc];
        u.w = *(const unsigned short*)&t[rr4 + 3][cc];
        *(ushort4*)(wT + (long)(c0 + cc) * RT + r0 + rr4) = u;
    }
}

// ---- elementwise / rowwise ----
__global__ void cvt_k(const float* __restrict__ in, _Float16* __restrict__ out, long n)
{
    long i = ((long)blockIdx.x * 256 + threadIdx.x) * 4;
    if (i >= n) return;
    const float4 v = *(const float4*)(in + i);
    out[i] = (_Float16)v.x; out[i + 1] = (_Float16)v.y;
    out[i + 2] = (_Float16)v.z; out[i + 3] = (_Float16)v.w;
}

__global__ void cvtT_k(const float* __restrict__ in, _Float16* __restrict__ out, int R, int C)
{
    __shared__ _Float16 t[64][65];
    const int c0 = blockIdx.x * 64, r0 = blockIdx.y * 64;
    const int tid = threadIdx.x;
    for (int i = 0; i < 16; ++i) {
        const int lin = i * 256 + tid;
        const int r = lin >> 6, cc = lin & 63;
        t[r][cc] = (_Float16)in[(long)(r0 + r) * C + c0 + cc];
    }
    __syncthreads();
    for (int i = 0; i < 16; ++i) {
        const int lin = i * 256 + tid;
        const int r2 = lin >> 6, c2 = lin & 63;
        out[(long)(c0 + r2) * R + r0 + c2] = t[c2][r2];
    }
}

__global__ void l2n16s_k(const float* __restrict__ in, long ld,
                         _Float16* __restrict__ out, float scale)
{
    const long row = blockIdx.x;
    const float* p = in + row * ld;
    _Float16* q = out + row * DD;
    const int t = threadIdx.x;
    float e0 = p[t], e1 = p[t + 256], e2 = p[t + 512], e3 = p[t + 768];
    __shared__ float rq[256];
    rq[t] = e0 * e0 + e1 * e1 + e2 * e2 + e3 * e3;
    __syncthreads();
    for (int k = 128; k; k >>= 1) { if (t < k) rq[t] += rq[t + k]; __syncthreads(); }
    const float f = scale / fmaxf(sqrtf(rq[0]), 1e-12f);
    q[t] = (_Float16)(e0 * f); q[t + 256] = (_Float16)(e1 * f);
    q[t + 512] = (_Float16)(e2 * f); q[t + 768] = (_Float16)(e3 * f);
}

// fused q + k l2norm from F32QK [2080][2048]
__global__ void l2qk_k(const float* __restrict__ qk, _Float16* __restrict__ q16,
                       _Float16* __restrict__ k16)
{
    const int blk = blockIdx.x;     // 0..3103
    const float* p; _Float16* o; float scale;
    if (blk < 1024) {
        const int b = blk >> 9, r = blk & 511;
        p = qk + (long)(b * SB + PPc + CC + r) * 2048;
        o = q16 + (long)blk * DD; scale = 32.f;
    } else {
        const int row = blk - 1024;
        p = qk + (long)row * 2048 + 1024;
        o = k16 + (long)row * DD; scale = 1.f;
    }
    const int t = threadIdx.x;
    float e0 = p[t], e1 = p[t + 256], e2 = p[t + 512], e3 = p[t + 768];
    __shared__ float rq[256];
    rq[t] = e0 * e0 + e1 * e1 + e2 * e2 + e3 * e3;
    __syncthreads();
    for (int k = 128; k; k >>= 1) { if (t < k) rq[t] += rq[t + k]; __syncthreads(); }
    const float f = scale / fmaxf(sqrtf(rq[0]), 1e-12f);
    o[t] = (_Float16)(e0 * f); o[t + 256] = (_Float16)(e1 * f);
    o[t + 512] = (_Float16)(e2 * f); o[t + 768] = (_Float16)(e3 * f);
}

// h rows come as two split-K halves (h + h2) plus bias hb, summed here
__global__ void lnaug_k(const float* __restrict__ x, const float* __restrict__ pers,
                        const float* __restrict__ h, const float* __restrict__ h2,
                        const float* __restrict__ hb,
                        const float* __restrict__ g, const float* __restrict__ b,
                        _Float16* __restrict__ out, int c)
{
    const int row = blockIdx.x;             // 0..2079
    const int bb = row / SB, i = row % SB;
    const float* p;
    const float* p2 = nullptr;
    if (i < PPc) p = pers + (long)i * DD;
    else if (i < PPc + CC) {
        const long off = (long)(bb * CC + i - PPc) * DD;
        p = h + off; p2 = h2 + off;
    }
    else p = x + (long)(bb * TT + c * CC + (i - PPc - CC)) * DD;
    _Float16* q = out + (long)row * DD;
    const int t = threadIdx.x;
    float e0 = p[t], e1 = p[t + 256], e2 = p[t + 512], e3 = p[t + 768];
    if (p2) {
        e0 += p2[t]       + hb[t];
        e1 += p2[t + 256] + hb[t + 256];
        e2 += p2[t + 512] + hb[t + 512];
        e3 += p2[t + 768] + hb[t + 768];
    }
    __shared__ float rs[256], rq[256];
    rs[t] = e0 + e1 + e2 + e3;
    rq[t] = e0 * e0 + e1 * e1 + e2 * e2 + e3 * e3;
    __syncthreads();
    for (int k = 128; k; k >>= 1) {
        if (t < k) { rs[t] += rs[t + k]; rq[t] += rq[t + k]; }
        __syncthreads();
    }
    const float mean = rs[0] * (1.f / DD);
    const float inv = rsqrtf(rq[0] * (1.f / DD) - mean * mean + 1e-5f);
    q[t]       = (_Float16)((e0 - mean) * inv * g[t]       + b[t]);
    q[t + 256] = (_Float16)((e1 - mean) * inv * g[t + 256] + b[t + 256]);
    q[t + 512] = (_Float16)((e2 - mean) * inv * g[t + 512] + b[t + 512]);
    q[t + 768] = (_Float16)((e3 - mean) * inv * g[t + 768] + b[t + 768]);
}

__global__ void softmax16_k(const float* __restrict__ sc, _Float16* __restrict__ pr)
{
    const int blk = blockIdx.x;             // 0..1023
    const int r = blk & 511;
    const int i = PPc + CC + r;
    const float* p = sc + (long)blk * SB;
    _Float16* q = pr + (long)blk * KA;
    const int t = threadIdx.x;
    __shared__ float red[256];
    float mx = -3.0e38f;
    for (int j = t; j < SB; j += 256)
        if (j <= i) mx = fmaxf(mx, p[j]);
    red[t] = mx; __syncthreads();
    for (int k = 128; k; k >>= 1) { if (t < k) red[t] = fmaxf(red[t], red[t + k]); __syncthreads(); }
    mx = red[0]; __syncthreads();
    float sum = 0.f;
    for (int j = t; j < SB; j += 256)
        if (j <= i) sum += __expf(p[j] - mx);
    red[t] = sum; __syncthreads();
    for (int k = 128; k; k >>= 1) { if (t < k) red[t] += red[t + k]; __syncthreads(); }
    const float inv = 1.f / red[0];
    for (int j = t; j < KA; j += 256) {
        float e = 0.f;
        if (j < SB && j <= i) e = __expf(p[j] - mx) * inv;
        q[j] = (_Float16)e;
    }
}

// gp and mo each arrive as two split-K halves; mo gets bias mb added here
__global__ void gateln2_k(const float* __restrict__ yt,
                          const float* __restrict__ gp, const float* __restrict__ gp2,
                          const float* __restrict__ mo, const float* __restrict__ mo2,
                          const float* __restrict__ mb,
                          const float* __restrict__ g, const float* __restrict__ b,
                          float* __restrict__ OF, _Float16* __restrict__ o16)
{
    const long row = blockIdx.x;
    const int t = threadIdx.x;
    float e[4];
    __shared__ float rs[256], rq[256];
    float ssum = 0.f, qsum = 0.f;
#pragma unroll
    for (int k = 0; k < 4; ++k) {
        const int cc = t + k * 256;
        const long idx = row * DD + cc;
        const float gv = gp[idx] + gp2[idx];
        const float mv = mo[idx] + mo2[idx] + mb[cc];
        const float s = 1.f / (1.f + __expf(-gv));
        e[k] = yt[idx] * s + mv * (1.f - s);
        OF[idx] = e[k];
        ssum += e[k]; qsum += e[k] * e[k];
    }
    rs[t] = ssum; rq[t] = qsum;
    __syncthreads();
    for (int k = 128; k; k >>= 1) {
        if (t < k) { rs[t] += rs[t + k]; rq[t] += rq[t + k]; }
        __syncthreads();
    }
    const float mean = rs[0] * (1.f / DD);
    const float inv = rsqrtf(rq[0] * (1.f / DD) - mean * mean + 1e-5f);
#pragma unroll
    for (int k = 0; k < 4; ++k) {
        const int cc = t + k * 256;
        o16[row * DD + cc] = (_Float16)((e[k] - mean) * inv * g[cc] + b[cc]);
    }
}

// FFN2 split-K consumer: out = h0 + h1 + bias + OF  (batch-aware addressing)
__global__ void ffnout_k(const float* __restrict__ h0, const float* __restrict__ h1,
                         const float* __restrict__ bias, const float* __restrict__ OF,
                         float* __restrict__ out, int c)
{
    const int row = blockIdx.x;            // 0..1023 (b*512 + rr)
    const int b = row >> 9, rr = row & 511;
    const int t = threadIdx.x;
    const long src = (long)row * DD;
    float* o = out + (long)b * TT * DD + (long)(c * CC + rr) * DD;
#pragma unroll
    for (int k = 0; k < 4; ++k) {
        const int cc = t + k * 256;
        o[cc] = h0[src + cc] + h1[src + cc] + bias[cc] + OF[src + cc];
    }
}

// fused tail: blocks 0..3071 rowsum + bias momentum update (rT16->mb1, da0T->mb0);
// 3072..4095 l2norm(F32A row)->qm16; 4096..5119 LN(YTF row)->gl16
__global__ void tailfuse_k(const _Float16* __restrict__ rT, const _Float16* __restrict__ daT,
                           float* __restrict__ mb0, float* __restrict__ mob0,
                           float* __restrict__ mb1, float* __restrict__ mob1,
                           const float* __restrict__ qmp, _Float16* __restrict__ qm16,
                           const float* __restrict__ ytf, const float* __restrict__ gg,
                           const float* __restrict__ gb, _Float16* __restrict__ gl)
{
    const int blk = blockIdx.x;
    const int t = threadIdx.x;
    __shared__ float rs[256], rq[256];
    if (blk < 3072) {
        const _Float16* p = (blk < 1024) ? rT + (long)blk * 1024
                                         : daT + (long)(blk - 1024) * 1024;
        rs[t] = (float)p[t] + (float)p[t + 256] + (float)p[t + 512] + (float)p[t + 768];
        __syncthreads();
        for (int k = 128; k; k >>= 1) { if (t < k) rs[t] += rs[t + k]; __syncthreads(); }
        if (t == 0) {
            const float d = rs[0];
            if (blk < 1024) {
                const float m = 0.9f * mob1[blk] + d;
                mob1[blk] = m;
                mb1[blk] = 0.99f * mb1[blk] - 0.01f * m;
            } else {
                const int j = blk - 1024;
                const float m = 0.9f * mob0[j] + d;
                mob0[j] = m;
                mb0[j] = 0.99f * mb0[j] - 0.01f * m;
            }
        }
    } else if (blk < 4096) {
        const long row = blk - 3072;
        const float* p = qmp + row * DD;
        _Float16* q = qm16 + row * DD;
        float e0 = p[t], e1 = p[t + 256], e2 = p[t + 512], e3 = p[t + 768];
        rq[t] = e0 * e0 + e1 * e1 + e2 * e2 + e3 * e3;
        __syncthreads();
        for (int k = 128; k; k >>= 1) { if (t < k) rq[t] += rq[t + k]; __syncthreads(); }
        const float f = 1.f / fmaxf(sqrtf(rq[0]), 1e-12f);
        q[t] = (_Float16)(e0 * f); q[t + 256] = (_Float16)(e1 * f);
        q[t + 512] = (_Float16)(e2 * f); q[t + 768] = (_Float16)(e3 * f);
    } else {
        const long row = blk - 4096;
        const float* p = ytf + row * DD;
        _Float16* q = gl + row * DD;
        float e0 = p[t], e1 = p[t + 256], e2 = p[t + 512], e3 = p[t + 768];
        rs[t] = e0 + e1 + e2 + e3;
        rq[t] = e0 * e0 + e1 * e1 + e2 * e2 + e3 * e3;
        __syncthreads();
        for (int k = 128; k; k >>= 1) {
            if (t < k) { rs[t] += rs[t + k]; rq[t] += rq[t + k]; }
            __syncthreads();
        }
        const float mean = rs[0] * (1.f / DD);
        const float inv = rsqrtf(rq[0] * (1.f / DD) - mean * mean + 1e-5f);
        q[t]       = (_Float16)((e0 - mean) * inv * gg[t]       + gb[t]);
        q[t + 256] = (_Float16)((e1 - mean) * inv * gg[t + 256] + gb[t + 256]);
        q[t + 512] = (_Float16)((e2 - mean) * inv * gg[t + 512] + gb[t + 512]);
        q[t + 768] = (_Float16)((e3 - mean) * inv * gg[t + 768] + gb[t + 768]);
    }
}

__global__ void zero_k(float* __restrict__ p, long n)
{
    long i = (long)blockIdx.x * 256 + threadIdx.x;
    const long st = (long)gridDim.x * 256;
    for (; i < n; i += st) p[i] = 0.f;
}

extern "C" void kernel_launch(void* const* d_in, const int* in_sizes, int n_in,
                              void* d_out, int out_size, void* d_ws, size_t ws_size,
                              hipStream_t stream)
{
    const float* x          = (const float*)d_in[0];
    const float* wq_ctx     = (const float*)d_in[1];
    const float* wq         = (const float*)d_in[2];
    const float* wk         = (const float*)d_in[3];
    const float* wv         = (const float*)d_in[4];
    const float* w_attn_out = (const float*)d_in[5];
    const float* w_gate     = (const float*)d_in[6];
    const float* gate_g     = (const float*)d_in[7];
    const float* gate_b     = (const float*)d_in[8];
    const float* n1_g       = (const float*)d_in[9];
    const float* n1_b       = (const float*)d_in[10];
    const float* n2_g       = (const float*)d_in[11];
    const float* n2_b       = (const float*)d_in[12];
    const float* ffn_w1     = (const float*)d_in[13];
    const float* ffn_b1     = (const float*)d_in[14];
    const float* ffn_w2     = (const float*)d_in[15];
    const float* ffn_b2     = (const float*)d_in[16];
    const float* pers       = (const float*)d_in[17];
    const float* mem_w0_in  = (const float*)d_in[18];
    const float* mem_b0_in  = (const float*)d_in[19];
    const float* mem_w1_in  = (const float*)d_in[20];
    const float* mem_b1_in  = (const float*)d_in[21];
    const float* mem_wk     = (const float*)d_in[22];
    const float* mem_wv     = (const float*)d_in[23];
    float* out = (float*)d_out;
    (void)in_sizes; (void)n_in; (void)out_size; (void)ws_size;

    char* cur = (char*)d_ws;
    auto allocF = [&](size_t n) { float* p = (float*)cur; cur += n * 4; return p; };
    auto allocH = [&](size_t n) { _Float16* p = (_Float16*)cur; cur += n * 2; return p; };

    float* mw0   = allocF((size_t)DD * HH);
    float* mw1   = allocF((size_t)HH * DD);
    float* mb0   = allocF(HH);
    float* mb1   = allocF(DD);
    float* mom   = allocF((size_t)DD * HH * 2 + HH + DD);
    float* mom_w0 = mom, *mom_w1 = mom + (size_t)DD * HH;
    float* mom_b0 = mom_w1 + (size_t)HH * DD, *mom_b1 = mom_b0 + HH;
    float* F32A  = allocF((size_t)1024 * DD);
    float* F32B  = allocF((size_t)1024 * DD);
    float* F32C  = allocF((size_t)1024 * HH);
    float* F32QK = allocF((size_t)2112 * 2048);
    float* YTF   = allocF((size_t)1024 * DD);
    float* OF    = allocF((size_t)1024 * DD);

    _Float16* x16    = allocH((size_t)2 * TT * DD);
    _Float16* wqcT   = allocH((size_t)DD * DD);
    _Float16* wqkT   = allocH((size_t)2048 * DD);
    _Float16* wvT    = allocH((size_t)DD * DD);
    _Float16* waoT   = allocH((size_t)DD * DD);
    _Float16* wgT    = allocH((size_t)DD * DD);
    _Float16* wmixT  = allocH((size_t)3072 * DD);
    _Float16* f1T    = allocH((size_t)FFd * DD);
    _Float16* f2T    = allocH((size_t)DD * FFd);
    _Float16* w0T    = allocH((size_t)HH * DD);
    _Float16* w1T    = allocH((size_t)DD * HH);
    _Float16* w1p    = allocH((size_t)HH * DD);
    _Float16* xn16   = allocH((size_t)2 * TT * DD);   // all chunks, x16 row order
    _Float16* h116   = allocH((size_t)1024 * HH);
    _Float16* laug16 = allocH((size_t)2208 * DD);
    _Float16* q16    = allocH((size_t)1024 * DD);
    _Float16* k16    = allocH((size_t)2208 * DD);
    _Float16* vT16   = allocH((size_t)2 * DD * KA);
    _Float16* pr16   = allocH((size_t)2 * 512 * KA);
    _Float16* ao16   = allocH((size_t)1024 * DD);
    _Float16* yt16   = allocH((size_t)1024 * DD);
    _Float16* kk16   = allocH((size_t)1024 * DD);
    _Float16* kkT16  = allocH((size_t)DD * 1024);
    _Float16* hs16   = allocH((size_t)1024 * HH);
    _Float16* hsT16  = allocH((size_t)HH * 1024);
    _Float16* r16    = allocH((size_t)1024 * DD);
    _Float16* rT16   = allocH((size_t)DD * 1024);
    _Float16* da0T   = allocH((size_t)HH * 1024);
    _Float16* qm16   = allocH((size_t)1024 * DD);
    _Float16* a216   = allocH((size_t)1024 * HH);
    _Float16* gl16   = allocH((size_t)1024 * DD);
    _Float16* h216   = allocH((size_t)1024 * DD);
    _Float16* f116   = allocH((size_t)1024 * FFd);

    // split-K z=1 scratch (inside F32QK, free at the relevant points)
    float* SPL0 = F32QK;                               // 4 MB
    float* SPL1 = F32QK + (size_t)1024 * 1024;         // 4 MB
    // XN_ALL (8192x1024 f32, 32 MB) aliases F32C..OF (33.3 MB contiguous),
    // consumed before the chunk loop's first use of those buffers.
    float* XN = F32C;

    auto launch = [&](int nz, GP g) {
        if (!g.ldA) g.ldA = g.K;
        if (!g.ldB) g.ldB = g.K;
        dim3 grid((g.N + 63) / 64, (g.M + 63) / 64, nz);
        gemm16<64, 64><<<grid, 256, 0, stream>>>(g);
    };

    // ---- init ----
    hipMemcpyAsync(mw0, mem_w0_in, sizeof(float) * DD * HH, hipMemcpyDeviceToDevice, stream);
    hipMemcpyAsync(mw1, mem_w1_in, sizeof(float) * HH * DD, hipMemcpyDeviceToDevice, stream);
    hipMemcpyAsync(mb0, mem_b0_in, sizeof(float) * HH, hipMemcpyDeviceToDevice, stream);
    hipMemcpyAsync(mb1, mem_b1_in, sizeof(float) * DD, hipMemcpyDeviceToDevice, stream);
    zero_k<<<4096, 256, 0, stream>>>(mom, (long)DD * HH * 2 + HH + DD);
    cvt_k<<<(2 * TT * DD) / 1024, 256, 0, stream>>>(x, x16, (long)2 * TT * DD);
    auto T64 = [&](const float* in, _Float16* o, int R, int C) {
        cvtT_k<<<dim3(C / 64, R / 64), 256, 0, stream>>>(in, o, R, C);
    };
    T64(wq_ctx, wqcT, DD, DD);
    T64(wq, wqkT, DD, DD); T64(wk, wqkT + (size_t)1024 * DD, DD, DD);
    T64(wv, wvT, DD, DD); T64(w_attn_out, waoT, DD, DD); T64(w_gate, wgT, DD, DD);
    T64(mem_wk, wmixT, DD, DD); T64(mem_wv, wmixT + (size_t)1024 * DD, DD, DD);
    T64(wq_ctx, wmixT + (size_t)2048 * DD, DD, DD);
    T64(ffn_w1, f1T, DD, FFd); T64(ffn_w2, f2T, FFd, DD);
    T64(mem_w0_in, w0T, DD, HH); T64(mem_w1_in, w1T, HH, DD);
    cvt_k<<<(HH * DD) / 1024, 256, 0, stream>>>(mem_w1_in, w1p, (long)HH * DD);

    // ---- hoisted step 1 (all chunks): XN = x16 @ wqcT, l2norm -> xn16 ----
    {
        GP g{}; g.A = x16; g.Bt = wqcT; g.Cf = XN; g.ldc = DD;
        g.s1 = 1.f; g.M = 2 * TT; g.N = DD; g.K = DD;
        launch(1, g);                                  // 2048 blocks, 8/CU
        l2n16s_k<<<2 * TT, 256, 0, stream>>>(XN, DD, xn16, 1.f);
    }

    for (int c = 0; c < NCH; ++c) {
        GP g;
        // 2. h = mem_mlp(mem, xn)   (z=2 over batch, xn slice per chunk)
        g = GP{}; g.A = xn16 + (long)c * CC * DD; g.bsA = (long)TT * DD;
        g.Bt = w0T; g.bias = mb0; g.Ch = h116; g.ldh = HH; g.bsH = (long)CC * HH;
        g.s1 = 1.f; g.M = CC; g.N = HH; g.K = DD; g.act = 1;
        launch(2, g);
        // 2b split-K x2 (NO bias here; mb1 added in lnaug): halves -> F32B, SPL0
        g = GP{}; g.A = h116; g.bsA = 1024; g.ldA = HH;
        g.Bt = w1T; g.bsB = 1024; g.ldB = HH;
        g.Cf = F32B; g.ldc = DD; g.bsC = (long)(SPL0 - F32B);
        g.s1 = 1.f; g.M = 1024; g.N = DD; g.K = 1024;
        launch(2, g);
        lnaug_k<<<2 * SB, 256, 0, stream>>>(x, pers, F32B, SPL0, mb1, n1_g, n1_b, laug16, c);
        // 3. q|k fused
        g = GP{}; g.A = laug16; g.Bt = wqkT; g.Cf = F32QK; g.ldc = 2048;
        g.s1 = 1.f; g.M = 2 * SB; g.N = 2048; g.K = DD;
        launch(1, g);
        l2qk_k<<<3104, 256, 0, stream>>>(F32QK, q16, k16);
        // 4. v (transposed out)
        g = GP{}; g.A = laug16; g.bsA = (long)SB * DD; g.Bt = wvT;
        g.Ct = vT16; g.ldt = KA; g.bsT = (long)DD * KA;
        g.s1 = 1.f; g.M = SB; g.N = DD; g.K = DD;
        launch(2, g);
        // 5. scores + softmax + PV
        g = GP{}; g.A = q16; g.bsA = (long)512 * DD; g.Bt = k16; g.bsB = (long)SB * DD;
        g.Cf = F32C; g.ldc = SB; g.bsC = (long)512 * SB;
        g.s1 = 1.f; g.M = 512; g.N = SB; g.K = DD;
        launch(2, g);
        softmax16_k<<<1024, 256, 0, stream>>>(F32C, pr16);
        g = GP{}; g.A = pr16; g.bsA = (long)512 * KA; g.Bt = vT16; g.bsB = (long)DD * KA;
        g.Ch = ao16; g.ldh = DD; g.bsH = (long)512 * DD;
        g.s1 = 1.f; g.M = 512; g.N = DD; g.K = KA;
        launch(2, g);
        // 6. y_t = seg + attn @ wao
        g = GP{}; g.A = ao16; g.bsA = (long)512 * DD; g.Bt = waoT;
        g.resid = x + (long)c * CC * DD; g.ldr = DD; g.bsR = (long)TT * DD;
        g.Cf = YTF; g.ldc = DD; g.bsC = (long)512 * DD;
        g.Ch = yt16; g.ldh = DD; g.bsH = (long)512 * DD;
        g.s1 = 1.f; g.s2 = 1.f; g.M = 512; g.N = DD; g.K = DD;
        launch(2, g);
        // 7. kk | vv | qm_pre fused (act 4) with kkT via LDS transpose
        g = GP{}; g.A = yt16; g.Bt = wmixT; g.Ch = kk16; g.Ct = kkT16; g.ldt = 1024;
        g.Cf = F32B; g.Cf2 = F32A;
        g.s1 = 1.f; g.M = 1024; g.N = 3072; g.K = DD; g.act = 4;
        launch(1, g);
        // 8. a0 = kk@w0+b0 (raw) ; hs/hsT = silu
        g = GP{}; g.A = kk16; g.Bt = w0T; g.bias = mb0; g.Cf = F32C; g.ldc = HH;
        g.Ch = hs16; g.ldh = HH; g.Ct = hsT16; g.ldt = 1024;
        g.s1 = 1.f; g.M = 1024; g.N = HH; g.K = DD; g.act = 1;
        launch(1, g);
        // 9. r = (hs@w1 + b1 - vv)/1024
        g = GP{}; g.A = hs16; g.Bt = w1T; g.bias = mb1;
        g.resid = F32B; g.ldr = DD;
        g.Ch = r16; g.ldh = DD; g.Ct = rT16; g.ldt = 1024;
        g.s1 = 1.f / 1024.f; g.s2 = -1.f / 1024.f; g.M = 1024; g.N = DD; g.K = HH;
        launch(1, g);
        // 10. da0T = (r @ w1_old^T) * dsilu(a0)   (before w1 update!)
        g = GP{}; g.A = r16; g.Bt = w1p; g.aux = F32C; g.ldx = HH;
        g.Ct = da0T; g.ldt = 1024;
        g.s1 = 1.f; g.M = 1024; g.N = HH; g.K = DD; g.act = 2;
        launch(1, g);
        // fused tail: rowsums + bias momentum update | l2norm(qm_pre) | LN(YTF)
        tailfuse_k<<<5120, 256, 0, stream>>>(rT16, da0T, mb0, mom_b0, mb1, mom_b1,
                                             F32A, qm16, YTF, gate_g, gate_b, gl16);
        // 11a. dW1 = hsT @ rT (plain GEMM, f32 -> F32C; F32C free after step 10)
        g = GP{}; g.A = hsT16; g.Bt = rT16; g.Cf = F32C; g.ldc = DD;
        g.s1 = 1.f; g.M = HH; g.N = DD; g.K = 1024;
        launch(1, g);
        // 11b. dW0 = kkT @ da0T (plain GEMM, f32 -> F32QK tail; free after l2qk)
        g = GP{}; g.A = kkT16; g.Bt = da0T; g.Cf = F32QK + (size_t)2048 * 1024; g.ldc = HH;
        g.s1 = 1.f; g.M = DD; g.N = HH; g.K = 1024;
        launch(1, g);
        // 11c. fused momentum + weight update + f16 cast + transpose (both weights)
        momupT_k<<<1024, 256, 0, stream>>>(F32C, mom_w1, mw1, w1p, w1T,
                                           F32QK + (size_t)2048 * 1024, mom_w0, mw0, w0T);
        // 13. mem_out = mem_mlp(new mem, qm16)
        g = GP{}; g.A = qm16; g.Bt = w0T; g.bias = mb0; g.Ch = a216; g.ldh = HH;
        g.s1 = 1.f; g.M = 1024; g.N = HH; g.K = DD; g.act = 1;
        launch(1, g);
        // 13b split-K x2 (NO bias; mb1 added in gateln2): halves -> F32B, SPL0
        g = GP{}; g.A = a216; g.bsA = 1024; g.ldA = HH;
        g.Bt = w1T; g.bsB = 1024; g.ldB = HH;
        g.Cf = F32B; g.ldc = DD; g.bsC = (long)(SPL0 - F32B);
        g.s1 = 1.f; g.M = 1024; g.N = DD; g.K = 1024;
        launch(2, g);
        // 14 split-K x2: gate proj halves -> F32C (z0) and SPL1 (z1); no bias in ref
        g = GP{}; g.A = gl16; g.bsA = 512; g.ldA = DD;
        g.Bt = wgT; g.bsB = 512; g.ldB = DD;
        g.Cf = F32C; g.ldc = DD; g.bsC = (long)(SPL1 - F32C);
        g.s1 = 1.f; g.M = 1024; g.N = DD; g.K = 512;
        launch(2, g);
        gateln2_k<<<1024, 256, 0, stream>>>(YTF, F32C, SPL1, F32B, SPL0, mb1,
                                            n2_g, n2_b, OF, h216);
        // 15. FFN
        g = GP{}; g.A = h216; g.Bt = f1T; g.bias = ffn_b1; g.Ch = f116; g.ldh = FFd;
        g.s1 = 1.f; g.M = 1024; g.N = FFd; g.K = DD; g.act = 1;
        launch(1, g);
        // 15b split-K x2 (M=1024 both batches; halves -> F32B, SPL0; consumer
        // ffnout adds bias + OF residual and scatters per-batch into out)
        g = GP{}; g.A = f116; g.bsA = 2048; g.ldA = FFd;
        g.Bt = f2T; g.bsB = 2048; g.ldB = FFd;
        g.Cf = F32B; g.ldc = DD; g.bsC = (long)(SPL0 - F32B);
        g.s1 = 1.f; g.M = 1024; g.N = DD; g.K = 2048;
        launch(2, g);
        ffnout_k<<<1024, 256, 0, stream>>>(F32B, SPL0, ffn_b2, OF,
                                           out, c);
    }
}